// Round 12
// baseline (1027.845 us; speedup 1.0000x reference)
//
#include <hip/hip_runtime.h>
#include <math.h>

#define EPSN 1e-5f
#define NB 1024u  // mega grid size (4 blocks/CU x 256 CUs, co-resident)

typedef __attribute__((ext_vector_type(8))) short bf16x8;
typedef __attribute__((ext_vector_type(4))) float f32x4;

__device__ __forceinline__ ushort f2bf(float f) {
  unsigned u = __float_as_uint(f);
  unsigned r = (u + 0x7fff + ((u >> 16) & 1)) >> 16;
  return (ushort)r;
}

// ---------------- block-wide reductions (blockDim.x == 256, 4 waves) --------
__device__ __forceinline__ float breduce_sum(float v, float* lds) {
#pragma unroll
  for (int o = 32; o > 0; o >>= 1) v += __shfl_down(v, o);
  int lane = threadIdx.x & 63, wid = threadIdx.x >> 6;
  __syncthreads();
  if (lane == 0) lds[wid] = v;
  __syncthreads();
  return lds[0] + lds[1] + lds[2] + lds[3];
}

__device__ __forceinline__ float breduce_max(float v, float* lds) {
#pragma unroll
  for (int o = 32; o > 0; o >>= 1) v = fmaxf(v, __shfl_down(v, o));
  int lane = threadIdx.x & 63, wid = threadIdx.x >> 6;
  __syncthreads();
  if (lane == 0) lds[wid] = v;
  __syncthreads();
  return fmaxf(fmaxf(lds[0], lds[1]), fmaxf(lds[2], lds[3]));
}

__device__ __forceinline__ void breduce2(float& a, float& b, float* lds) {
#pragma unroll
  for (int o = 32; o > 0; o >>= 1) {
    a += __shfl_down(a, o);
    b += __shfl_down(b, o);
  }
  int lane = threadIdx.x & 63, wid = threadIdx.x >> 6;
  __syncthreads();
  if (lane == 0) { lds[wid] = a; lds[4 + wid] = b; }
  __syncthreads();
  a = lds[0] + lds[1] + lds[2] + lds[3];
  b = lds[4] + lds[5] + lds[6] + lds[7];
}

// ---------------- device-scope grid barrier (all blocks co-resident) --------
__device__ __forceinline__ void gsync(unsigned* bar, unsigned target) {
  __syncthreads();
  if (threadIdx.x == 0) {
    __threadfence();                // release
    atomicAdd(bar, 1u);
    while (__hip_atomic_load(bar, __ATOMIC_RELAXED, __HIP_MEMORY_SCOPE_AGENT) <
           target)
      __builtin_amdgcn_s_sleep(8);
    __threadfence();                // acquire
  }
  __syncthreads();
}

// ---------------- pre: bf16 converts + resd memset + barrier zero -----------
__global__ void pre_kernel(const float* __restrict__ gus,
                           const float* __restrict__ wdown,
                           const float* __restrict__ wfuse,
                           ushort* __restrict__ gus_bf,
                           ushort* __restrict__ wdown_bf,
                           ushort* __restrict__ wfuse_bf,
                           ushort* __restrict__ resd, unsigned* __restrict__ bar) {
  int bid = blockIdx.x, tid = threadIdx.x;
  if (bid == 0 && tid == 0) *bar = 0u;
  if (bid < 2048) {
    int i = bid * 1024 + tid * 4;
    const float* src; ushort* dst; int off;
    if (i < 1048576) { src = gus; dst = gus_bf; off = i; }
    else if (i < 1572864) { src = wdown; dst = wdown_bf; off = i - 1048576; }
    else { src = wfuse; dst = wfuse_bf; off = i - 1572864; }
    float4 v = *(const float4*)&src[off];
    ushort4 o = {f2bf(v.x), f2bf(v.y), f2bf(v.z), f2bf(v.w)};
    *(ushort4*)&dst[off] = o;
  } else {
    int t8 = (bid - 2048) * 256 + tid;
    uint4 z = {0u, 0u, 0u, 0u};
#pragma unroll
    for (int k = 0; k < 4; ++k) *(uint4*)&resd[(size_t)(t8 + k * 65536) * 8] = z;
  }
}

// ---------------- SKConv finish (2-row tile, wave-pair per channel) ---------
__device__ __forceinline__ void finish3(float a[2][4], float bv, int m, int c,
                                        int y0, int xb, float* feas,
                                        float* bmean, float* red) {
  int tid = threadIdx.x, lane = tid & 63, wid = tid >> 6, pr = wid >> 1;
  float s = 0.f, ss = 0.f;
#pragma unroll
  for (int rr = 0; rr < 2; ++rr)
#pragma unroll
    for (int px = 0; px < 4; ++px) {
      a[rr][px] += bv;
      s += a[rr][px];
      ss += a[rr][px] * a[rr][px];
    }
#pragma unroll
  for (int o = 32; o > 0; o >>= 1) {
    s += __shfl_down(s, o);
    ss += __shfl_down(ss, o);
  }
  __syncthreads();
  if (lane == 0) { red[wid] = s; red[4 + wid] = ss; }
  __syncthreads();
  s = red[2 * pr] + red[2 * pr + 1];
  ss = red[4 + 2 * pr] + red[4 + 2 * pr + 1];
  float mean = s * (1.f / 1024.f);
  float var = ss * (1.f / 1024.f) - mean * mean;
  float inv = rsqrtf(var + EPSN);
  float rs = 0.f;
#pragma unroll
  for (int rr = 0; rr < 2; ++rr) {
    float4 o4;
    float* ov = (float*)&o4;
#pragma unroll
    for (int px = 0; px < 4; ++px) {
      float v = (a[rr][px] - mean) * inv;
      v = v > 0.f ? v : 0.f;
      ov[px] = v;
      rs += v;
    }
    *(float4*)&feas[(size_t)(m * 512 + c) * 1024 + (y0 + rr) * 32 + xb] = o4;
  }
#pragma unroll
  for (int o = 32; o > 0; o >>= 1) rs += __shfl_down(rs, o);
  __syncthreads();
  if (lane == 0) red[wid] = rs;
  __syncthreads();
  if ((tid & 127) == 0)
    bmean[m * 512 + c] = (red[2 * pr] + red[2 * pr + 1]) * (1.f / 1024.f);
}

// ---------------- SKConv v5: LDS-broadcast weights + stride-48 staging ------
__global__ __launch_bounds__(256) void sk_all5(
    const float* __restrict__ x, const float* __restrict__ w3,
    const float* __restrict__ b3, const float* __restrict__ w5,
    const float* __restrict__ b5, const float* __restrict__ w7,
    const float* __restrict__ b7, float* __restrict__ feas,
    float* __restrict__ bmean) {
  __shared__ float chanp[8 * 1536];    // 8 ch x (32 rows x stride48), x at col 4
  __shared__ float ws7p[2 * 16 * 56];  // [ch][ic][7 rows x 8 pad]
  __shared__ float ws5p[2 * 16 * 40];  // [ch][ic][5 rows x 8 pad]
  __shared__ float ws3p[2 * 16 * 12];  // [ch][ic][3 rows x 4 pad]
  __shared__ float red[8];
  int bid = blockIdx.x, tid = threadIdx.x;
  int c0 = bid * 2, g = c0 >> 4;
  for (int i = tid; i < 8 * 1536; i += 256) chanp[i] = 0.f;
  for (int i = tid; i < 1792; i += 256) {
    int cw = i / 896, rem = i - cw * 896;
    int ic = rem / 56, t = rem - ic * 56, r = t >> 3, k = t & 7;
    ws7p[i] = (r < 7 && k < 7) ? w7[(c0 + cw) * 784 + ic * 49 + r * 7 + k] : 0.f;
  }
  for (int i = tid; i < 1280; i += 256) {
    int cw = i / 640, rem = i - cw * 640;
    int ic = rem / 40, t = rem - ic * 40, r = t >> 3, k = t & 7;
    ws5p[i] = (r < 5 && k < 5) ? w5[(c0 + cw) * 400 + ic * 25 + r * 5 + k] : 0.f;
  }
  for (int i = tid; i < 384; i += 256) {
    int cw = i / 192, rem = i - cw * 192;
    int ic = rem / 12, t = rem - ic * 12, r = t >> 2, k = t & 3;
    ws3p[i] = (k < 3) ? w3[(c0 + cw) * 144 + ic * 9 + r * 3 + k] : 0.f;
  }
  int ch = tid >> 7;  // wave pair -> output channel
  int idx = tid & 127;
  int y0 = (idx >> 3) * 2, xb = (idx & 7) * 4;
  float a7[2][4] = {}, a5[2][4] = {}, a3[2][4] = {};
  int srow = tid >> 3, scol = (tid & 7) * 4;
  for (int half = 0; half < 2; ++half) {
    __syncthreads();
#pragma unroll
    for (int j = 0; j < 8; ++j) {
      float4 xv = *(const float4*)&x[(size_t)(g * 16 + half * 8 + j) * 1024 + tid * 4];
      *(float4*)&chanp[j * 1536 + srow * 48 + 4 + scol] = xv;
    }
    __syncthreads();
    for (int cc = 0; cc < 8; ++cc) {
      int ic = half * 8 + cc;
      float sg[8][12];
#pragma unroll
      for (int s = 0; s < 8; ++s) {
        int r = y0 - 3 + s;
        if ((unsigned)r < 32u) {
          const float* rp = &chanp[cc * 1536 + r * 48 + xb];
          float4 q0 = *(const float4*)rp;
          float4 q1 = *(const float4*)(rp + 4);
          float4 q2 = *(const float4*)(rp + 8);
          sg[s][0] = q0.x; sg[s][1] = q0.y; sg[s][2] = q0.z; sg[s][3] = q0.w;
          sg[s][4] = q1.x; sg[s][5] = q1.y; sg[s][6] = q1.z; sg[s][7] = q1.w;
          sg[s][8] = q2.x; sg[s][9] = q2.y; sg[s][10] = q2.z; sg[s][11] = q2.w;
        } else {
#pragma unroll
          for (int t = 0; t < 12; ++t) sg[s][t] = 0.f;
        }
      }
      const float* W7 = &ws7p[ch * 896 + ic * 56];
      const float* W5 = &ws5p[ch * 640 + ic * 40];
      const float* W3 = &ws3p[ch * 192 + ic * 12];
#pragma unroll
      for (int dy = 0; dy < 7; ++dy) {
        float4 wa = *(const float4*)(W7 + dy * 8);
        float4 wb = *(const float4*)(W7 + dy * 8 + 4);
        float wv[7] = {wa.x, wa.y, wa.z, wa.w, wb.x, wb.y, wb.z};
#pragma unroll
        for (int kx = 0; kx < 7; ++kx)
#pragma unroll
          for (int px = 0; px < 4; ++px) {
            a7[0][px] += sg[dy][px + kx + 1] * wv[kx];
            a7[1][px] += sg[dy + 1][px + kx + 1] * wv[kx];
          }
      }
#pragma unroll
      for (int d5 = 0; d5 < 5; ++d5) {
        float4 va = *(const float4*)(W5 + d5 * 8);
        float wv[5] = {va.x, va.y, va.z, va.w, W5[d5 * 8 + 4]};
#pragma unroll
        for (int kx = 0; kx < 5; ++kx)
#pragma unroll
          for (int px = 0; px < 4; ++px) {
            a5[0][px] += sg[d5 + 1][px + kx + 2] * wv[kx];
            a5[1][px] += sg[d5 + 2][px + kx + 2] * wv[kx];
          }
      }
#pragma unroll
      for (int d3 = 0; d3 < 3; ++d3) {
        float4 ta = *(const float4*)(W3 + d3 * 4);
        float wv[3] = {ta.x, ta.y, ta.z};
#pragma unroll
        for (int kx = 0; kx < 3; ++kx)
#pragma unroll
          for (int px = 0; px < 4; ++px) {
            a3[0][px] += sg[d3 + 2][px + kx + 3] * wv[kx];
            a3[1][px] += sg[d3 + 3][px + kx + 3] * wv[kx];
          }
      }
    }
  }
  int c = c0 + ch;
  finish3(a3, b3[c], 0, c, y0, xb, feas, bmean, red);
  finish3(a5, b5[c], 1, c, y0, xb, feas, bmean, red);
  finish3(a7, b7[c], 2, c, y0, xb, feas, bmean, red);
}

// ---------------- blend + FC-attention; writes res, Zt2 res-half, resd ------
__global__ __launch_bounds__(256) void blend_fc(
    const float* __restrict__ feas, const float* __restrict__ bmean,
    const float* __restrict__ wfc, const float* __restrict__ bfc,
    const float* __restrict__ w0, const float* __restrict__ b0,
    const float* __restrict__ w1, const float* __restrict__ b1,
    const float* __restrict__ w2, const float* __restrict__ b2,
    float* __restrict__ res, ushort* __restrict__ Zt2,
    ushort* __restrict__ resd) {
  __shared__ float sfea[512];
  __shared__ float zpart[8][32];
  __shared__ float zz[32];
  __shared__ float lv[3][32];
  __shared__ float attb[3][32];
  __shared__ float tile[32][33];
  int tid = threadIdx.x;
  int pb = blockIdx.x * 32, cb = blockIdx.y * 32;
  for (int c = tid; c < 512; c += 256)
    sfea[c] = bmean[c] + bmean[512 + c] + bmean[1024 + c];
  __syncthreads();
  {
    int j = tid & 31, seg = tid >> 5;
    float p = 0.f;
    for (int c = seg * 64; c < seg * 64 + 64; ++c) p += sfea[c] * wfc[j * 512 + c];
    zpart[seg][j] = p;
  }
  __syncthreads();
  if (tid < 32) {
    float d = bfc[tid];
#pragma unroll
    for (int s = 0; s < 8; ++s) d += zpart[s][tid];
    zz[tid] = d;
  }
  __syncthreads();
  if (tid < 96) {
    int m = tid >> 5, cl = tid & 31;
    const float* wm = (m == 0) ? w0 : (m == 1) ? w1 : w2;
    const float* bm = (m == 0) ? b0 : (m == 1) ? b1 : b2;
    float l = bm[cb + cl];
#pragma unroll
    for (int j = 0; j < 32; ++j) l += zz[j] * wm[(cb + cl) * 32 + j];
    lv[m][cl] = l;
  }
  __syncthreads();
  if (tid < 32) {
    float l0 = lv[0][tid], l1 = lv[1][tid], l2 = lv[2][tid];
    float mx = fmaxf(l0, fmaxf(l1, l2));
    float e0 = expf(l0 - mx), e1 = expf(l1 - mx), e2 = expf(l2 - mx);
    float inv = 1.f / (e0 + e1 + e2);
    attb[0][tid] = e0 * inv; attb[1][tid] = e1 * inv; attb[2][tid] = e2 * inv;
  }
  __syncthreads();
  int tx = tid & 31, ty = tid >> 5;
  int pos = pb + tx;
  int yy = pos >> 5, xx = pos & 31;
  int ki0 = (yy + 1) & 1, pi0 = (yy + 1 - ki0) >> 1;
  int kj0 = (xx + 1) & 1, pj0 = (xx + 1 - kj0) >> 1;
#pragma unroll
  for (int r = 0; r < 4; ++r) {
    int cl = ty + r * 8;
    int c = cb + cl;
    float v = feas[c * 1024 + pos] * attb[0][cl] +
              feas[(512 + c) * 1024 + pos] * attb[1][cl] +
              feas[(1024 + c) * 1024 + pos] * attb[2][cl];
    res[c * 1024 + pos] = v;
    tile[cl][tx] = v;
    ushort bv16 = f2bf(v);
#pragma unroll
    for (int ai = 0; ai < 2; ++ai) {
      int ki = ki0 + 2 * ai, pi = pi0 - ai;
      if ((unsigned)pi >= 16u) continue;
#pragma unroll
      for (int aj = 0; aj < 2; ++aj) {
        int kj = kj0 + 2 * aj, pj = pj0 - aj;
        if ((unsigned)pj >= 16u) continue;
        resd[((size_t)(ki * 4 + kj) << 17) + (size_t)c * 256 + pi * 16 + pj] = bv16;
      }
    }
  }
  __syncthreads();
#pragma unroll
  for (int r = 0; r < 4; ++r) {
    int pl = ty + r * 8;
    Zt2[(size_t)(pb + pl) * 1024 + 512 + cb + tx] = f2bf(tile[tx][pl]);
  }
}

// ---------------- persistent mega kernel: 9 stages, 8 grid barriers ---------
__global__ __launch_bounds__(256, 4) void mega(
    const float* __restrict__ res, float* __restrict__ Apart,
    ushort* __restrict__ attnT, const ushort* __restrict__ resd,
    float* __restrict__ T, float* __restrict__ orlt, float* __restrict__ sigt,
    ushort* __restrict__ orlT, const ushort* __restrict__ gus_bf,
    ushort* __restrict__ Zt, const ushort* __restrict__ wdown_bf,
    float* __restrict__ rawP, ushort* __restrict__ Zt2,
    const ushort* __restrict__ wfuse_bf, float* __restrict__ out,
    unsigned* __restrict__ bar) {
  __shared__ float smem[1320];
  float* red = smem + 1296;
  float* a9s = smem + 1304;
  int bid = blockIdx.x, tid = threadIdx.x;

  // ---- S0: gram partials (512 blocks; 16 ch each) ----
  if (bid < 512) {
    float (*ch)[324] = (float(*)[324])smem;
    int qb = (bid & 3) * 64, pb = ((bid >> 2) & 3) * 64, kc = bid >> 4;
    int tx = tid & 15, ty = tid >> 4;
    for (int i = tid; i < 4 * 324; i += 256) smem[i] = 0.f;
    int pi = (pb + ty * 4) >> 4, pj = (pb + ty * 4) & 15;
    int qi = (qb + tx * 4) >> 4, qj = (qb + tx * 4) & 15;
    int lane = tid & 63, wv = tid >> 6;
    int sr = lane >> 2, sc = (lane & 3) * 4;
    float acc[4][4] = {};
    for (int c0 = kc * 16; c0 < kc * 16 + 16; c0 += 4) {
      __syncthreads();
      {
        const float* src = res + (size_t)(c0 + wv) * 1024 + (2 * sr) * 32 + 2 * sc;
        float4 r0a = *(const float4*)src;
        float4 r0b = *(const float4*)(src + 4);
        float4 r1a = *(const float4*)(src + 32);
        float4 r1b = *(const float4*)(src + 36);
        float* dst = &ch[wv][(sr + 1) * 18 + sc + 1];
        dst[0] = 0.25f * (r0a.x + r0a.y + r1a.x + r1a.y);
        dst[1] = 0.25f * (r0a.z + r0a.w + r1a.z + r1a.w);
        dst[2] = 0.25f * (r0b.x + r0b.y + r1b.x + r1b.y);
        dst[3] = 0.25f * (r0b.z + r0b.w + r1b.z + r1b.w);
      }
      __syncthreads();
#pragma unroll
      for (int cc = 0; cc < 4; ++cc) {
        float ps[3][6], qs[3][6];
#pragma unroll
        for (int u = 0; u < 3; ++u) {
          const float* pr = &ch[cc][(pi + u) * 18 + pj];
          const float* qr = &ch[cc][(qi + u) * 18 + qj];
#pragma unroll
          for (int t = 0; t < 6; ++t) { ps[u][t] = pr[t]; qs[u][t] = qr[t]; }
        }
#pragma unroll
        for (int u = 0; u < 3; ++u)
#pragma unroll
          for (int v = 0; v < 3; ++v)
#pragma unroll
            for (int i = 0; i < 4; ++i)
#pragma unroll
              for (int j = 0; j < 4; ++j)
                acc[i][j] += ps[u][v + i] * qs[u][v + j];
      }
    }
#pragma unroll
    for (int i = 0; i < 4; ++i) {
      float4 o4 = {acc[i][0], acc[i][1], acc[i][2], acc[i][3]};
      *(float4*)&Apart[(size_t)kc * 65536 + (pb + ty * 4 + i) * 256 + qb + tx * 4] = o4;
    }
  }
  gsync(bar, NB * 1);

  // ---- S1: softmax + diag norm -> attnT (256 blocks) ----
  if (bid < 256) {
    int q = bid, t = tid;
    float d = 0.f, s = 0.f;
#pragma unroll
    for (int k = 0; k < 32; ++k) {
      d += Apart[(size_t)k * 65536 + t * 257];
      s += Apart[(size_t)k * 65536 + q * 256 + t];
    }
    float invn = 10.f / fmaxf(sqrtf(fmaxf(d, 0.f)), 1e-4f);
    float v = s * invn;
    float mx = breduce_max(v, red);
    float e = expf(v - mx);
    float sm = breduce_sum(e, red);
    attnT[q * 256 + t] = f2bf(e / sm);
  }
  gsync(bar, NB * 2);

  // ---- S2: tconv 16-batch MFMA (512 blocks) ----
  if (bid < 512) {
    int wv = tid >> 6, lane = tid & 63;
    int quad = lane >> 4, m16 = lane & 15;
    int nb = (bid & 7) * 64, qb = ((bid >> 3) & 3) * 64, b = bid >> 5;
    const ushort* Ap = attnT + (size_t)(qb + wv * 16 + m16) * 256 + quad * 8;
    const ushort* Bp = resd + (size_t)b * 131072 + (size_t)(nb + m16) * 256 + quad * 8;
    f32x4 ac0 = {0.f, 0.f, 0.f, 0.f}, ac1 = ac0, ac2 = ac0, ac3 = ac0;
#pragma unroll 2
    for (int k0 = 0; k0 < 256; k0 += 32) {
      bf16x8 af = *(const bf16x8*)(Ap + k0);
      bf16x8 b0 = *(const bf16x8*)(Bp + k0);
      bf16x8 b1 = *(const bf16x8*)(Bp + 16 * 256 + k0);
      bf16x8 b2 = *(const bf16x8*)(Bp + 32 * 256 + k0);
      bf16x8 b3 = *(const bf16x8*)(Bp + 48 * 256 + k0);
      ac0 = __builtin_amdgcn_mfma_f32_16x16x32_bf16(af, b0, ac0, 0, 0, 0);
      ac1 = __builtin_amdgcn_mfma_f32_16x16x32_bf16(af, b1, ac1, 0, 0, 0);
      ac2 = __builtin_amdgcn_mfma_f32_16x16x32_bf16(af, b2, ac2, 0, 0, 0);
      ac3 = __builtin_amdgcn_mfma_f32_16x16x32_bf16(af, b3, ac3, 0, 0, 0);
    }
    int row = qb + wv * 16 + quad * 4;
    float* Cb = T + (size_t)b * 131072;
    f32x4 accs[4] = {ac0, ac1, ac2, ac3};
#pragma unroll
    for (int nt = 0; nt < 4; ++nt)
#pragma unroll
      for (int r = 0; r < 4; ++r)
        Cb[(size_t)(row + r) * 512 + nb + nt * 16 + m16] = accs[nt][r];
  }
  gsync(bar, NB * 3);

  // ---- S3: tcomb -> orlt, sigt, orlT (512 blocks) ----
  if (bid < 512) {
    float (*tl)[33] = (float(*)[33])smem;
    int nb = (bid & 31) * 32, cb = ((bid >> 5) & 15) * 32;
    int tx = tid & 31, ty = tid >> 5;
#pragma unroll
    for (int r = 0; r < 4; ++r) {
      int nl = ty + r * 8;
      int n = nb + nl, c = cb + tx;
      int y = n >> 5, x = n & 31;
      int i0 = (y + 1) >> 1, ki0 = (y + 1) & 1;
      int j0 = (x + 1) >> 1, kj0 = (x + 1) & 1;
      float sum = 0.f;
#pragma unroll
      for (int iy = 0; iy < 2; ++iy) {
        int i = i0 - iy, ki = ki0 + 2 * iy;
        if ((unsigned)i >= 16u) continue;
#pragma unroll
        for (int ix = 0; ix < 2; ++ix) {
          int j = j0 - ix, kj = kj0 + 2 * ix;
          if ((unsigned)j >= 16u) continue;
          sum += T[((ki * 4 + kj) * 256 + i * 16 + j) * 512 + c];
        }
      }
      float v = sum * 0.25f;
      orlt[n * 512 + c] = v;
      sigt[n * 512 + c] = 1.f / (1.f + expf(-v));
      tl[nl][tx] = v;
    }
    __syncthreads();
#pragma unroll
    for (int r = 0; r < 4; ++r) {
      int cl = ty + r * 8;
      orlT[(size_t)(cb + cl) * 1024 + nb + tx] = f2bf(tl[tx][cl]);
    }
  }
  gsync(bar, NB * 4);

  // ---- S4: gus GEMM (blocks 896..1023) + CSA (all 1024) -> Zt ----
  if (bid >= 896) {
    const int K = 1024;
    int gb = bid - 896;
    int wv = tid >> 6, lane = tid & 63;
    int quad = lane >> 4, m16 = lane & 15;
    int nb = (gb & 7) * 64, mb = (gb >> 3) * 64;
    const ushort* Ap = gus_bf + (size_t)(mb + wv * 16 + m16) * K + quad * 8;
    const ushort* Bp = orlT + (size_t)(nb + m16) * K + quad * 8;
    f32x4 ac0 = {0.f, 0.f, 0.f, 0.f}, ac1 = ac0, ac2 = ac0, ac3 = ac0;
#pragma unroll 2
    for (int k0 = 0; k0 < K; k0 += 32) {
      bf16x8 af = *(const bf16x8*)(Ap + k0);
      bf16x8 b0 = *(const bf16x8*)(Bp + k0);
      bf16x8 b1 = *(const bf16x8*)(Bp + (size_t)16 * K + k0);
      bf16x8 b2 = *(const bf16x8*)(Bp + (size_t)32 * K + k0);
      bf16x8 b3 = *(const bf16x8*)(Bp + (size_t)48 * K + k0);
      ac0 = __builtin_amdgcn_mfma_f32_16x16x32_bf16(af, b0, ac0, 0, 0, 0);
      ac1 = __builtin_amdgcn_mfma_f32_16x16x32_bf16(af, b1, ac1, 0, 0, 0);
      ac2 = __builtin_amdgcn_mfma_f32_16x16x32_bf16(af, b2, ac2, 0, 0, 0);
      ac3 = __builtin_amdgcn_mfma_f32_16x16x32_bf16(af, b3, ac3, 0, 0, 0);
    }
    int row = mb + wv * 16 + quad * 4;
    f32x4 accs[4] = {ac0, ac1, ac2, ac3};
#pragma unroll
    for (int nt = 0; nt < 4; ++nt) {
      int c = nb + nt * 16 + m16;
#pragma unroll
      for (int r = 0; r < 4; ++r) {
        int p = row + r;
        int pos = ((p & 1) << 9) + c;
        int kk = p >> 1;
        Zt[(size_t)pos * 1024 + kk] = f2bf(accs[nt][r]);
      }
    }
  }
  {  // CSA for n = bid (all 1024 blocks)
    int n = bid;
    int ny = n >> 5, nx = n & 31;
    int c2 = tid * 2;
    float2 ctr = *(const float2*)&sigt[n * 512 + c2];
    float part[9];
#pragma unroll
    for (int u = 0; u < 3; ++u) {
      int yy = ny + u - 1;
#pragma unroll
      for (int v = 0; v < 3; ++v) {
        int xx = nx + v - 1;
        float2 nb2 = {0.f, 0.f};
        if ((unsigned)yy < 32u && (unsigned)xx < 32u)
          nb2 = *(const float2*)&sigt[(yy * 32 + xx) * 512 + c2];
        part[u * 3 + v] = ctr.x * nb2.x + ctr.y * nb2.y;
      }
    }
    float a[9];
#pragma unroll
    for (int t = 0; t < 9; ++t) a[t] = breduce_sum(part[t], red) * (1.f / 512.f);
    float mx = a[0];
#pragma unroll
    for (int t = 1; t < 9; ++t) mx = fmaxf(mx, a[t]);
    float sum = 0.f;
#pragma unroll
    for (int t = 0; t < 9; ++t) { a[t] = expf(a[t] - mx); sum += a[t]; }
    if (tid == 0) {
      float inv = 1.f / sum;
#pragma unroll
      for (int t = 0; t < 9; ++t) a9s[t] = a[t] * inv;
    }
    __syncthreads();
    float2 acc = {0.f, 0.f};
#pragma unroll
    for (int u = 0; u < 3; ++u) {
      int yy = ny + u - 1;
#pragma unroll
      for (int v = 0; v < 3; ++v) {
        int xx = nx + v - 1;
        if ((unsigned)yy < 32u && (unsigned)xx < 32u) {
          float w = a9s[u * 3 + v];
          float2 ov = *(const float2*)&orlt[(yy * 32 + xx) * 512 + c2];
          acc.x += w * ov.x;
          acc.y += w * ov.y;
        }
      }
    }
    int kk = 512 + (n >> 1);
    int pos0 = ((n & 1) << 9) + c2;
    Zt[(size_t)pos0 * 1024 + kk] = f2bf(acc.x);
    Zt[(size_t)(pos0 + 1) * 1024 + kk] = f2bf(acc.y);
  }
  gsync(bar, NB * 5);

  // ---- S5: down GEMM K-split (256 blocks) ----
  if (bid < 256) {
    const int KF = 1024;
    int wv = tid >> 6, lane = tid & 63;
    int quad = lane >> 4, m16 = lane & 15;
    int nb = (bid & 15) * 64, mb = ((bid >> 4) & 7) * 64, kh = bid >> 7;
    const ushort* Ap = wdown_bf + (size_t)(mb + wv * 16 + m16) * KF + kh * 512 + quad * 8;
    const ushort* Bp = Zt + (size_t)(nb + m16) * KF + kh * 512 + quad * 8;
    f32x4 ac0 = {0.f, 0.f, 0.f, 0.f}, ac1 = ac0, ac2 = ac0, ac3 = ac0;
#pragma unroll 2
    for (int k0 = 0; k0 < 512; k0 += 32) {
      bf16x8 af = *(const bf16x8*)(Ap + k0);
      bf16x8 b0 = *(const bf16x8*)(Bp + k0);
      bf16x8 b1 = *(const bf16x8*)(Bp + (size_t)16 * KF + k0);
      bf16x8 b2 = *(const bf16x8*)(Bp + (size_t)32 * KF + k0);
      bf16x8 b3 = *(const bf16x8*)(Bp + (size_t)48 * KF + k0);
      ac0 = __builtin_amdgcn_mfma_f32_16x16x32_bf16(af, b0, ac0, 0, 0, 0);
      ac1 = __builtin_amdgcn_mfma_f32_16x16x32_bf16(af, b1, ac1, 0, 0, 0);
      ac2 = __builtin_amdgcn_mfma_f32_16x16x32_bf16(af, b2, ac2, 0, 0, 0);
      ac3 = __builtin_amdgcn_mfma_f32_16x16x32_bf16(af, b3, ac3, 0, 0, 0);
    }
    int row = mb + wv * 16 + quad * 4;
    float* C = rawP + (size_t)kh * 524288;
    f32x4 accs[4] = {ac0, ac1, ac2, ac3};
#pragma unroll
    for (int nt = 0; nt < 4; ++nt)
#pragma unroll
      for (int r = 0; r < 4; ++r)
        C[(size_t)(row + r) * 1024 + nb + nt * 16 + m16] = accs[nt][r];
  }
  gsync(bar, NB * 6);

  // ---- S6: norm_down -> Zt2 first half (512 blocks) ----
  if (bid < 512) {
    int c = bid;
    float v[4];
    float s = 0.f, ss = 0.f;
#pragma unroll
    for (int r = 0; r < 4; ++r) {
      int i = c * 1024 + tid + r * 256;
      v[r] = rawP[i] + rawP[524288 + i];
      s += v[r];
      ss += v[r] * v[r];
    }
    breduce2(s, ss, red);
    float mean = s * (1.f / 1024.f);
    float var = ss * (1.f / 1024.f) - mean * mean;
    float inv = rsqrtf(var + EPSN);
#pragma unroll
    for (int r = 0; r < 4; ++r) {
      float t = (v[r] - mean) * inv;
      t = t >= 0.f ? t : 0.2f * t;
      Zt2[(size_t)(tid + r * 256) * 1024 + c] = f2bf(t);
    }
  }
  gsync(bar, NB * 7);

  // ---- S7: fuse GEMM K-split (256 blocks) ----
  if (bid < 256) {
    const int KF = 1024;
    int wv = tid >> 6, lane = tid & 63;
    int quad = lane >> 4, m16 = lane & 15;
    int nb = (bid & 15) * 64, mb = ((bid >> 4) & 7) * 64, kh = bid >> 7;
    const ushort* Ap = wfuse_bf + (size_t)(mb + wv * 16 + m16) * KF + kh * 512 + quad * 8;
    const ushort* Bp = Zt2 + (size_t)(nb + m16) * KF + kh * 512 + quad * 8;
    f32x4 ac0 = {0.f, 0.f, 0.f, 0.f}, ac1 = ac0, ac2 = ac0, ac3 = ac0;
#pragma unroll 2
    for (int k0 = 0; k0 < 512; k0 += 32) {
      bf16x8 af = *(const bf16x8*)(Ap + k0);
      bf16x8 b0 = *(const bf16x8*)(Bp + k0);
      bf16x8 b1 = *(const bf16x8*)(Bp + (size_t)16 * KF + k0);
      bf16x8 b2 = *(const bf16x8*)(Bp + (size_t)32 * KF + k0);
      bf16x8 b3 = *(const bf16x8*)(Bp + (size_t)48 * KF + k0);
      ac0 = __builtin_amdgcn_mfma_f32_16x16x32_bf16(af, b0, ac0, 0, 0, 0);
      ac1 = __builtin_amdgcn_mfma_f32_16x16x32_bf16(af, b1, ac1, 0, 0, 0);
      ac2 = __builtin_amdgcn_mfma_f32_16x16x32_bf16(af, b2, ac2, 0, 0, 0);
      ac3 = __builtin_amdgcn_mfma_f32_16x16x32_bf16(af, b3, ac3, 0, 0, 0);
    }
    int row = mb + wv * 16 + quad * 4;
    float* C = rawP + (size_t)kh * 524288;
    f32x4 accs[4] = {ac0, ac1, ac2, ac3};
#pragma unroll
    for (int nt = 0; nt < 4; ++nt)
#pragma unroll
      for (int r = 0; r < 4; ++r)
        C[(size_t)(row + r) * 1024 + nb + nt * 16 + m16] = accs[nt][r];
  }
  gsync(bar, NB * 8);

  // ---- S8: final norm -> out (512 blocks) ----
  if (bid < 512) {
    int c = bid;
    float v[4];
    float s = 0.f, ss = 0.f;
#pragma unroll
    for (int r = 0; r < 4; ++r) {
      int i = c * 1024 + tid + r * 256;
      v[r] = rawP[i] + rawP[524288 + i];
      s += v[r];
      ss += v[r] * v[r];
    }
    breduce2(s, ss, red);
    float mean = s * (1.f / 1024.f);
    float var = ss * (1.f / 1024.f) - mean * mean;
    float inv = rsqrtf(var + EPSN);
#pragma unroll
    for (int r = 0; r < 4; ++r) {
      float t = (v[r] - mean) * inv;
      out[c * 1024 + tid + r * 256] = t >= 0.f ? t : 0.2f * t;
    }
  }
}

// ---------------- host launch ------------------------------------------------
extern "C" void kernel_launch(void* const* d_in, const int* in_sizes, int n_in,
                              void* d_out, int out_size, void* d_ws, size_t ws_size,
                              hipStream_t stream) {
  const float* x = (const float*)d_in[0];
  const float* gus = (const float*)d_in[1];
  const float* w3 = (const float*)d_in[2];
  const float* b3 = (const float*)d_in[3];
  const float* w5 = (const float*)d_in[4];
  const float* b5 = (const float*)d_in[5];
  const float* w7 = (const float*)d_in[6];
  const float* b7 = (const float*)d_in[7];
  const float* wfc = (const float*)d_in[8];
  const float* bfc = (const float*)d_in[9];
  const float* w0 = (const float*)d_in[10];
  const float* b0 = (const float*)d_in[11];
  const float* w1 = (const float*)d_in[12];
  const float* b1 = (const float*)d_in[13];
  const float* w2 = (const float*)d_in[14];
  const float* b2 = (const float*)d_in[15];
  const float* wdown = (const float*)d_in[16];
  const float* wfuse = (const float*)d_in[17];

  float* ws = (float*)d_ws;
  float* feas = ws;                      // 1572864 (dead after blend_fc)
  float* rawP = feas + 524288;           // 2x524288 fl partials
  float* bmean = ws + 1572864;           // 1536
  float* res = bmean + 1536;             // 524288
  float* Zt2f = res + 524288;            // 524288 fl
  ushort* Zt2 = (ushort*)Zt2f;
  float* T = Zt2f + 524288;              // 2097152
  float* Apart = T;                      // 32x65536 fl (dead before T written)
  ushort* Zt = (ushort*)T;               // (written after tcomb)
  float* orlt = T + 2097152;             // 524288
  float* sigt = orlt + 524288;           // 524288
  ushort* orlT = (ushort*)(sigt + 524288);        // 262144 fl
  ushort* attnT = (ushort*)(sigt + 786432);       // 32768 fl
  ushort* gus_bf = (ushort*)(sigt + 819200);      // 524288 fl
  ushort* wdown_bf = (ushort*)(sigt + 1343488);   // 262144 fl
  ushort* wfuse_bf = (ushort*)(sigt + 1605632);   // 262144 fl
  ushort* resd = (ushort*)(sigt + 1867776);       // 1048576 fl
  unsigned* bar = (unsigned*)(sigt + 2916352);    // barrier counter

  pre_kernel<<<2304, 256, 0, stream>>>(gus, wdown, wfuse, gus_bf, wdown_bf,
                                       wfuse_bf, resd, bar);
  sk_all5<<<256, 256, 0, stream>>>(x, w3, b3, w5, b5, w7, b7, feas, bmean);
  blend_fc<<<dim3(32, 16), 256, 0, stream>>>(feas, bmean, wfc, bfc, w0, b0, w1,
                                             b1, w2, b2, res, Zt2, resd);
  mega<<<NB, 256, 0, stream>>>(res, Apart, attnT, resd, T, orlt, sigt, orlT,
                               gus_bf, Zt, wdown_bf, rawP, Zt2, wfuse_bf,
                               (float*)d_out, bar);
}

// Round 13
// 259.939 us; speedup vs baseline: 3.9542x; 3.9542x over previous
//
#include <hip/hip_runtime.h>
#include <math.h>

#define EPSN 1e-5f

typedef __attribute__((ext_vector_type(8))) short bf16x8;
typedef __attribute__((ext_vector_type(4))) float f32x4;

__device__ __forceinline__ ushort f2bf(float f) {
  unsigned u = __float_as_uint(f);
  unsigned r = (u + 0x7fff + ((u >> 16) & 1)) >> 16;
  return (ushort)r;
}

// ---------------- block-wide reductions (blockDim.x == 256, 4 waves) --------
__device__ __forceinline__ void breduce2(float& a, float& b, float* lds) {
#pragma unroll
  for (int o = 32; o > 0; o >>= 1) {
    a += __shfl_down(a, o);
    b += __shfl_down(b, o);
  }
  int lane = threadIdx.x & 63, wid = threadIdx.x >> 6;
  __syncthreads();
  if (lane == 0) { lds[wid] = a; lds[4 + wid] = b; }
  __syncthreads();
  a = lds[0] + lds[1] + lds[2] + lds[3];
  b = lds[4] + lds[5] + lds[6] + lds[7];
}

__device__ __forceinline__ float breduce_sum(float v, float* lds) {
#pragma unroll
  for (int o = 32; o > 0; o >>= 1) v += __shfl_down(v, o);
  int lane = threadIdx.x & 63, wid = threadIdx.x >> 6;
  __syncthreads();
  if (lane == 0) lds[wid] = v;
  __syncthreads();
  return lds[0] + lds[1] + lds[2] + lds[3];
}

__device__ __forceinline__ float breduce_max(float v, float* lds) {
#pragma unroll
  for (int o = 32; o > 0; o >>= 1) v = fmaxf(v, __shfl_down(v, o));
  int lane = threadIdx.x & 63, wid = threadIdx.x >> 6;
  __syncthreads();
  if (lane == 0) lds[wid] = v;
  __syncthreads();
  return fmaxf(fmaxf(lds[0], lds[1]), fmaxf(lds[2], lds[3]));
}

// ---------------- pre: bf16 converts + resd memset --------------------------
__global__ void pre_kernel(const float* __restrict__ gus,
                           const float* __restrict__ wdown,
                           const float* __restrict__ wfuse,
                           ushort* __restrict__ gus_bf,
                           ushort* __restrict__ wdown_bf,
                           ushort* __restrict__ wfuse_bf,
                           ushort* __restrict__ resd) {
  int bid = blockIdx.x, tid = threadIdx.x;
  if (bid < 2048) {
    int i = bid * 1024 + tid * 4;
    const float* src; ushort* dst; int off;
    if (i < 1048576) { src = gus; dst = gus_bf; off = i; }
    else if (i < 1572864) { src = wdown; dst = wdown_bf; off = i - 1048576; }
    else { src = wfuse; dst = wfuse_bf; off = i - 1572864; }
    float4 v = *(const float4*)&src[off];
    ushort4 o = {f2bf(v.x), f2bf(v.y), f2bf(v.z), f2bf(v.w)};
    *(ushort4*)&dst[off] = o;
  } else {
    int t8 = (bid - 2048) * 256 + tid;
    uint4 z = {0u, 0u, 0u, 0u};
#pragma unroll
    for (int k = 0; k < 4; ++k) *(uint4*)&resd[(size_t)(t8 + k * 65536) * 8] = z;
  }
}

// ---------------- SKConv finish (2-row tile, wave-pair per channel) ---------
__device__ __forceinline__ void finish3(float a[2][4], float bv, int m, int c,
                                        int y0, int xb, float* feas,
                                        float* bmean, float* red) {
  int tid = threadIdx.x, lane = tid & 63, wid = tid >> 6, pr = wid >> 1;
  float s = 0.f, ss = 0.f;
#pragma unroll
  for (int rr = 0; rr < 2; ++rr)
#pragma unroll
    for (int px = 0; px < 4; ++px) {
      a[rr][px] += bv;
      s += a[rr][px];
      ss += a[rr][px] * a[rr][px];
    }
#pragma unroll
  for (int o = 32; o > 0; o >>= 1) {
    s += __shfl_down(s, o);
    ss += __shfl_down(ss, o);
  }
  __syncthreads();
  if (lane == 0) { red[wid] = s; red[4 + wid] = ss; }
  __syncthreads();
  s = red[2 * pr] + red[2 * pr + 1];
  ss = red[4 + 2 * pr] + red[4 + 2 * pr + 1];
  float mean = s * (1.f / 1024.f);
  float var = ss * (1.f / 1024.f) - mean * mean;
  float inv = rsqrtf(var + EPSN);
  float rs = 0.f;
#pragma unroll
  for (int rr = 0; rr < 2; ++rr) {
    float4 o4;
    float* ov = (float*)&o4;
#pragma unroll
    for (int px = 0; px < 4; ++px) {
      float v = (a[rr][px] - mean) * inv;
      v = v > 0.f ? v : 0.f;
      ov[px] = v;
      rs += v;
    }
    *(float4*)&feas[(size_t)(m * 512 + c) * 1024 + (y0 + rr) * 32 + xb] = o4;
  }
#pragma unroll
  for (int o = 32; o > 0; o >>= 1) rs += __shfl_down(rs, o);
  __syncthreads();
  if (lane == 0) red[wid] = rs;
  __syncthreads();
  if ((tid & 127) == 0)
    bmean[m * 512 + c] = (red[2 * pr] + red[2 * pr + 1]) * (1.f / 1024.f);
}

// ---------------- SKConv v5: LDS-broadcast weights + stride-48 staging ------
__global__ __launch_bounds__(256) void sk_all5(
    const float* __restrict__ x, const float* __restrict__ w3,
    const float* __restrict__ b3, const float* __restrict__ w5,
    const float* __restrict__ b5, const float* __restrict__ w7,
    const float* __restrict__ b7, float* __restrict__ feas,
    float* __restrict__ bmean) {
  __shared__ float chanp[8 * 1536];    // 8 ch x (32 rows x stride48), x at col 4
  __shared__ float ws7p[2 * 16 * 56];  // [ch][ic][7 rows x 8 pad]
  __shared__ float ws5p[2 * 16 * 40];  // [ch][ic][5 rows x 8 pad]
  __shared__ float ws3p[2 * 16 * 12];  // [ch][ic][3 rows x 4 pad]
  __shared__ float red[8];
  int bid = blockIdx.x, tid = threadIdx.x;
  int c0 = bid * 2, g = c0 >> 4;
  for (int i = tid; i < 8 * 1536; i += 256) chanp[i] = 0.f;
  for (int i = tid; i < 1792; i += 256) {
    int cw = i / 896, rem = i - cw * 896;
    int ic = rem / 56, t = rem - ic * 56, r = t >> 3, k = t & 7;
    ws7p[i] = (r < 7 && k < 7) ? w7[(c0 + cw) * 784 + ic * 49 + r * 7 + k] : 0.f;
  }
  for (int i = tid; i < 1280; i += 256) {
    int cw = i / 640, rem = i - cw * 640;
    int ic = rem / 40, t = rem - ic * 40, r = t >> 3, k = t & 7;
    ws5p[i] = (r < 5 && k < 5) ? w5[(c0 + cw) * 400 + ic * 25 + r * 5 + k] : 0.f;
  }
  for (int i = tid; i < 384; i += 256) {
    int cw = i / 192, rem = i - cw * 192;
    int ic = rem / 12, t = rem - ic * 12, r = t >> 2, k = t & 3;
    ws3p[i] = (k < 3) ? w3[(c0 + cw) * 144 + ic * 9 + r * 3 + k] : 0.f;
  }
  int ch = tid >> 7;  // wave pair -> output channel
  int idx = tid & 127;
  int y0 = (idx >> 3) * 2, xb = (idx & 7) * 4;
  float a7[2][4] = {}, a5[2][4] = {}, a3[2][4] = {};
  int srow = tid >> 3, scol = (tid & 7) * 4;
  for (int half = 0; half < 2; ++half) {
    __syncthreads();
#pragma unroll
    for (int j = 0; j < 8; ++j) {
      float4 xv = *(const float4*)&x[(size_t)(g * 16 + half * 8 + j) * 1024 + tid * 4];
      *(float4*)&chanp[j * 1536 + srow * 48 + 4 + scol] = xv;
    }
    __syncthreads();
    for (int cc = 0; cc < 8; ++cc) {
      int ic = half * 8 + cc;
      float sg[8][12];
#pragma unroll
      for (int s = 0; s < 8; ++s) {
        int r = y0 - 3 + s;
        if ((unsigned)r < 32u) {
          const float* rp = &chanp[cc * 1536 + r * 48 + xb];
          float4 q0 = *(const float4*)rp;
          float4 q1 = *(const float4*)(rp + 4);
          float4 q2 = *(const float4*)(rp + 8);
          sg[s][0] = q0.x; sg[s][1] = q0.y; sg[s][2] = q0.z; sg[s][3] = q0.w;
          sg[s][4] = q1.x; sg[s][5] = q1.y; sg[s][6] = q1.z; sg[s][7] = q1.w;
          sg[s][8] = q2.x; sg[s][9] = q2.y; sg[s][10] = q2.z; sg[s][11] = q2.w;
        } else {
#pragma unroll
          for (int t = 0; t < 12; ++t) sg[s][t] = 0.f;
        }
      }
      const float* W7 = &ws7p[ch * 896 + ic * 56];
      const float* W5 = &ws5p[ch * 640 + ic * 40];
      const float* W3 = &ws3p[ch * 192 + ic * 12];
#pragma unroll
      for (int dy = 0; dy < 7; ++dy) {
        float4 wa = *(const float4*)(W7 + dy * 8);
        float4 wb = *(const float4*)(W7 + dy * 8 + 4);
        float wv[7] = {wa.x, wa.y, wa.z, wa.w, wb.x, wb.y, wb.z};
#pragma unroll
        for (int kx = 0; kx < 7; ++kx)
#pragma unroll
          for (int px = 0; px < 4; ++px) {
            a7[0][px] += sg[dy][px + kx + 1] * wv[kx];
            a7[1][px] += sg[dy + 1][px + kx + 1] * wv[kx];
          }
      }
#pragma unroll
      for (int d5 = 0; d5 < 5; ++d5) {
        float4 va = *(const float4*)(W5 + d5 * 8);
        float wv[5] = {va.x, va.y, va.z, va.w, W5[d5 * 8 + 4]};
#pragma unroll
        for (int kx = 0; kx < 5; ++kx)
#pragma unroll
          for (int px = 0; px < 4; ++px) {
            a5[0][px] += sg[d5 + 1][px + kx + 2] * wv[kx];
            a5[1][px] += sg[d5 + 2][px + kx + 2] * wv[kx];
          }
      }
#pragma unroll
      for (int d3 = 0; d3 < 3; ++d3) {
        float4 ta = *(const float4*)(W3 + d3 * 4);
        float wv[3] = {ta.x, ta.y, ta.z};
#pragma unroll
        for (int kx = 0; kx < 3; ++kx)
#pragma unroll
          for (int px = 0; px < 4; ++px) {
            a3[0][px] += sg[d3 + 2][px + kx + 3] * wv[kx];
            a3[1][px] += sg[d3 + 3][px + kx + 3] * wv[kx];
          }
      }
    }
  }
  int c = c0 + ch;
  finish3(a3, b3[c], 0, c, y0, xb, feas, bmean, red);
  finish3(a5, b5[c], 1, c, y0, xb, feas, bmean, red);
  finish3(a7, b7[c], 2, c, y0, xb, feas, bmean, red);
}

// ---------------- blend + FC-attention; writes res, Zt2 res-half, resd ------
__global__ __launch_bounds__(256) void blend_fc(
    const float* __restrict__ feas, const float* __restrict__ bmean,
    const float* __restrict__ wfc, const float* __restrict__ bfc,
    const float* __restrict__ w0, const float* __restrict__ b0,
    const float* __restrict__ w1, const float* __restrict__ b1,
    const float* __restrict__ w2, const float* __restrict__ b2,
    float* __restrict__ res, ushort* __restrict__ Zt2,
    ushort* __restrict__ resd) {
  __shared__ float sfea[512];
  __shared__ float zpart[8][32];
  __shared__ float zz[32];
  __shared__ float lv[3][32];
  __shared__ float attb[3][32];
  __shared__ float tile[32][33];
  int tid = threadIdx.x;
  int pb = blockIdx.x * 32, cb = blockIdx.y * 32;
  for (int c = tid; c < 512; c += 256)
    sfea[c] = bmean[c] + bmean[512 + c] + bmean[1024 + c];
  __syncthreads();
  {
    int j = tid & 31, seg = tid >> 5;
    float p = 0.f;
    for (int c = seg * 64; c < seg * 64 + 64; ++c) p += sfea[c] * wfc[j * 512 + c];
    zpart[seg][j] = p;
  }
  __syncthreads();
  if (tid < 32) {
    float d = bfc[tid];
#pragma unroll
    for (int s = 0; s < 8; ++s) d += zpart[s][tid];
    zz[tid] = d;
  }
  __syncthreads();
  if (tid < 96) {
    int m = tid >> 5, cl = tid & 31;
    const float* wm = (m == 0) ? w0 : (m == 1) ? w1 : w2;
    const float* bm = (m == 0) ? b0 : (m == 1) ? b1 : b2;
    float l = bm[cb + cl];
#pragma unroll
    for (int j = 0; j < 32; ++j) l += zz[j] * wm[(cb + cl) * 32 + j];
    lv[m][cl] = l;
  }
  __syncthreads();
  if (tid < 32) {
    float l0 = lv[0][tid], l1 = lv[1][tid], l2 = lv[2][tid];
    float mx = fmaxf(l0, fmaxf(l1, l2));
    float e0 = expf(l0 - mx), e1 = expf(l1 - mx), e2 = expf(l2 - mx);
    float inv = 1.f / (e0 + e1 + e2);
    attb[0][tid] = e0 * inv; attb[1][tid] = e1 * inv; attb[2][tid] = e2 * inv;
  }
  __syncthreads();
  int tx = tid & 31, ty = tid >> 5;
  int pos = pb + tx;
  int yy = pos >> 5, xx = pos & 31;
  int ki0 = (yy + 1) & 1, pi0 = (yy + 1 - ki0) >> 1;
  int kj0 = (xx + 1) & 1, pj0 = (xx + 1 - kj0) >> 1;
#pragma unroll
  for (int r = 0; r < 4; ++r) {
    int cl = ty + r * 8;
    int c = cb + cl;
    float v = feas[c * 1024 + pos] * attb[0][cl] +
              feas[(512 + c) * 1024 + pos] * attb[1][cl] +
              feas[(1024 + c) * 1024 + pos] * attb[2][cl];
    res[c * 1024 + pos] = v;
    tile[cl][tx] = v;
    ushort bv16 = f2bf(v);
#pragma unroll
    for (int ai = 0; ai < 2; ++ai) {
      int ki = ki0 + 2 * ai, pi = pi0 - ai;
      if ((unsigned)pi >= 16u) continue;
#pragma unroll
      for (int aj = 0; aj < 2; ++aj) {
        int kj = kj0 + 2 * aj, pj = pj0 - aj;
        if ((unsigned)pj >= 16u) continue;
        resd[((size_t)(ki * 4 + kj) << 17) + (size_t)c * 256 + pi * 16 + pj] = bv16;
      }
    }
  }
  __syncthreads();
#pragma unroll
  for (int r = 0; r < 4; ++r) {
    int pl = ty + r * 8;
    Zt2[(size_t)(pb + pl) * 1024 + 512 + cb + tx] = f2bf(tile[tx][pl]);
  }
}

// ---------------- Gram split-K partials, 16-ch chunks (512 blocks) ----------
__global__ __launch_bounds__(256) void gram_part2(const float* __restrict__ res,
                                                  float* __restrict__ Apart) {
  __shared__ float ch[4][324];
  int tid = threadIdx.x;
  int qb = blockIdx.x * 64, pb = blockIdx.y * 64;
  int kc = blockIdx.z;
  int tx = tid & 15, ty = tid >> 4;
  for (int i = tid; i < 4 * 324; i += 256) ((float*)ch)[i] = 0.f;
  int pi = (pb + ty * 4) >> 4, pj = (pb + ty * 4) & 15;
  int qi = (qb + tx * 4) >> 4, qj = (qb + tx * 4) & 15;
  int lane = tid & 63, wv = tid >> 6;
  int sr = lane >> 2, sc = (lane & 3) * 4;
  float acc[4][4] = {};
  for (int c0 = kc * 16; c0 < kc * 16 + 16; c0 += 4) {
    __syncthreads();
    {
      const float* src = res + (size_t)(c0 + wv) * 1024 + (2 * sr) * 32 + 2 * sc;
      float4 r0a = *(const float4*)src;
      float4 r0b = *(const float4*)(src + 4);
      float4 r1a = *(const float4*)(src + 32);
      float4 r1b = *(const float4*)(src + 36);
      float* dst = &ch[wv][(sr + 1) * 18 + sc + 1];
      dst[0] = 0.25f * (r0a.x + r0a.y + r1a.x + r1a.y);
      dst[1] = 0.25f * (r0a.z + r0a.w + r1a.z + r1a.w);
      dst[2] = 0.25f * (r0b.x + r0b.y + r1b.x + r1b.y);
      dst[3] = 0.25f * (r0b.z + r0b.w + r1b.z + r1b.w);
    }
    __syncthreads();
#pragma unroll
    for (int cc = 0; cc < 4; ++cc) {
      float ps[3][6], qs[3][6];
#pragma unroll
      for (int u = 0; u < 3; ++u) {
        const float* pr = &ch[cc][(pi + u) * 18 + pj];
        const float* qr = &ch[cc][(qi + u) * 18 + qj];
#pragma unroll
        for (int t = 0; t < 6; ++t) { ps[u][t] = pr[t]; qs[u][t] = qr[t]; }
      }
#pragma unroll
      for (int u = 0; u < 3; ++u)
#pragma unroll
        for (int v = 0; v < 3; ++v)
#pragma unroll
          for (int i = 0; i < 4; ++i)
#pragma unroll
            for (int j = 0; j < 4; ++j)
              acc[i][j] += ps[u][v + i] * qs[u][v + j];
    }
  }
#pragma unroll
  for (int i = 0; i < 4; ++i) {
    float4 o4 = {acc[i][0], acc[i][1], acc[i][2], acc[i][3]};
    *(float4*)&Apart[(size_t)kc * 65536 + (pb + ty * 4 + i) * 256 + qb + tx * 4] = o4;
  }
}

// ---------------- softmax + inline diag norm -> attnT bf16 ------------------
__global__ __launch_bounds__(256) void attn_soft3(const float* __restrict__ Apart,
                                                  ushort* __restrict__ attnT) {
  __shared__ float red[8];
  int q = blockIdx.x, t = threadIdx.x;
  float d = 0.f, s = 0.f;
#pragma unroll
  for (int k = 0; k < 32; ++k) {
    d += Apart[(size_t)k * 65536 + t * 257];
    s += Apart[(size_t)k * 65536 + q * 256 + t];
  }
  float invn = 10.f / fmaxf(sqrtf(fmaxf(d, 0.f)), 1e-4f);
  float v = s * invn;
  float mx = breduce_max(v, red);
  float e = expf(v - mx);
  float sm = breduce_sum(e, red);
  attnT[q * 256 + t] = f2bf(e / sm);
}

// ---------------- tconv: 16-batch bf16 MFMA GEMM ----------------------------
__global__ __launch_bounds__(256) void mfma_tconv(const ushort* __restrict__ attnT,
                                                  const ushort* __restrict__ resd,
                                                  float* __restrict__ T) {
  int tid = threadIdx.x;
  int wv = tid >> 6, lane = tid & 63;
  int quad = lane >> 4, m16 = lane & 15;
  int nb = blockIdx.x * 64, qb = blockIdx.y * 64;
  int b = blockIdx.z;
  const ushort* Ap = attnT + (size_t)(qb + wv * 16 + m16) * 256 + quad * 8;
  const ushort* Bp = resd + (size_t)b * 131072 + (size_t)(nb + m16) * 256 + quad * 8;
  f32x4 ac0 = {0.f, 0.f, 0.f, 0.f}, ac1 = ac0, ac2 = ac0, ac3 = ac0;
#pragma unroll 2
  for (int k0 = 0; k0 < 256; k0 += 32) {
    bf16x8 af = *(const bf16x8*)(Ap + k0);
    bf16x8 b0 = *(const bf16x8*)(Bp + k0);
    bf16x8 b1 = *(const bf16x8*)(Bp + 16 * 256 + k0);
    bf16x8 b2 = *(const bf16x8*)(Bp + 32 * 256 + k0);
    bf16x8 b3 = *(const bf16x8*)(Bp + 48 * 256 + k0);
    ac0 = __builtin_amdgcn_mfma_f32_16x16x32_bf16(af, b0, ac0, 0, 0, 0);
    ac1 = __builtin_amdgcn_mfma_f32_16x16x32_bf16(af, b1, ac1, 0, 0, 0);
    ac2 = __builtin_amdgcn_mfma_f32_16x16x32_bf16(af, b2, ac2, 0, 0, 0);
    ac3 = __builtin_amdgcn_mfma_f32_16x16x32_bf16(af, b3, ac3, 0, 0, 0);
  }
  int row = qb + wv * 16 + quad * 4;
  float* Cb = T + (size_t)b * 131072;
  f32x4 accs[4] = {ac0, ac1, ac2, ac3};
#pragma unroll
  for (int nt = 0; nt < 4; ++nt)
#pragma unroll
    for (int r = 0; r < 4; ++r)
      Cb[(size_t)(row + r) * 512 + nb + nt * 16 + m16] = accs[nt][r];
}

// ---------------- combine taps -> orlt, sigt, orlT bf16 (tiled) -------------
__global__ __launch_bounds__(256) void tcomb2(const float* __restrict__ T,
                                              float* __restrict__ orlt,
                                              float* __restrict__ sigt,
                                              ushort* __restrict__ orlT) {
  __shared__ float tl[32][33];
  int nb = blockIdx.x * 32, cb = blockIdx.y * 32;
  int tx = threadIdx.x & 31, ty = threadIdx.x >> 5;
#pragma unroll
  for (int r = 0; r < 4; ++r) {
    int nl = ty + r * 8;
    int n = nb + nl, c = cb + tx;
    int y = n >> 5, x = n & 31;
    int i0 = (y + 1) >> 1, ki0 = (y + 1) & 1;
    int j0 = (x + 1) >> 1, kj0 = (x + 1) & 1;
    float sum = 0.f;
#pragma unroll
    for (int iy = 0; iy < 2; ++iy) {
      int i = i0 - iy, ki = ki0 + 2 * iy;
      if ((unsigned)i >= 16u) continue;
#pragma unroll
      for (int ix = 0; ix < 2; ++ix) {
        int j = j0 - ix, kj = kj0 + 2 * ix;
        if ((unsigned)j >= 16u) continue;
        sum += T[((ki * 4 + kj) * 256 + i * 16 + j) * 512 + c];
      }
    }
    float v = sum * 0.25f;
    orlt[n * 512 + c] = v;
    sigt[n * 512 + c] = 1.f / (1.f + expf(-v));
    tl[nl][tx] = v;
  }
  __syncthreads();
#pragma unroll
  for (int r = 0; r < 4; ++r) {
    int cl = ty + r * 8;
    orlT[(size_t)(cb + cl) * 1024 + nb + tx] = f2bf(tl[tx][cl]);
  }
}

// ---------------- merged: gus GEMM (blocks 0..127) + CSA (128..1151) --------
__global__ __launch_bounds__(256) void gus_csa(
    const ushort* __restrict__ gus_bf, const ushort* __restrict__ orlT,
    const float* __restrict__ sigt, const float* __restrict__ orlt,
    ushort* __restrict__ Zt) {
  __shared__ float red[8];
  __shared__ float a9s[9];
  int tid = threadIdx.x;
  if (blockIdx.x < 128) {
    const int K = 1024;
    int wv = tid >> 6, lane = tid & 63;
    int quad = lane >> 4, m16 = lane & 15;
    int nb = (blockIdx.x & 7) * 64, mb = (blockIdx.x >> 3) * 64;
    const ushort* Ap = gus_bf + (size_t)(mb + wv * 16 + m16) * K + quad * 8;
    const ushort* Bp = orlT + (size_t)(nb + m16) * K + quad * 8;
    f32x4 ac0 = {0.f, 0.f, 0.f, 0.f}, ac1 = ac0, ac2 = ac0, ac3 = ac0;
#pragma unroll 2
    for (int k0 = 0; k0 < K; k0 += 32) {
      bf16x8 af = *(const bf16x8*)(Ap + k0);
      bf16x8 b0 = *(const bf16x8*)(Bp + k0);
      bf16x8 b1 = *(const bf16x8*)(Bp + (size_t)16 * K + k0);
      bf16x8 b2 = *(const bf16x8*)(Bp + (size_t)32 * K + k0);
      bf16x8 b3 = *(const bf16x8*)(Bp + (size_t)48 * K + k0);
      ac0 = __builtin_amdgcn_mfma_f32_16x16x32_bf16(af, b0, ac0, 0, 0, 0);
      ac1 = __builtin_amdgcn_mfma_f32_16x16x32_bf16(af, b1, ac1, 0, 0, 0);
      ac2 = __builtin_amdgcn_mfma_f32_16x16x32_bf16(af, b2, ac2, 0, 0, 0);
      ac3 = __builtin_amdgcn_mfma_f32_16x16x32_bf16(af, b3, ac3, 0, 0, 0);
    }
    int row = mb + wv * 16 + quad * 4;
    f32x4 accs[4] = {ac0, ac1, ac2, ac3};
#pragma unroll
    for (int nt = 0; nt < 4; ++nt) {
      int c = nb + nt * 16 + m16;
#pragma unroll
      for (int r = 0; r < 4; ++r) {
        int p = row + r;
        int pos = ((p & 1) << 9) + c;
        int kk = p >> 1;
        Zt[(size_t)pos * 1024 + kk] = f2bf(accs[nt][r]);
      }
    }
    return;
  }
  int n = blockIdx.x - 128;
  int ny = n >> 5, nx = n & 31;
  int c2 = tid * 2;
  float2 ctr = *(const float2*)&sigt[n * 512 + c2];
  float part[9];
#pragma unroll
  for (int u = 0; u < 3; ++u) {
    int yy = ny + u - 1;
#pragma unroll
    for (int v = 0; v < 3; ++v) {
      int xx = nx + v - 1;
      float2 nb2 = {0.f, 0.f};
      if ((unsigned)yy < 32u && (unsigned)xx < 32u)
        nb2 = *(const float2*)&sigt[(yy * 32 + xx) * 512 + c2];
      part[u * 3 + v] = ctr.x * nb2.x + ctr.y * nb2.y;
    }
  }
  float a[9];
#pragma unroll
  for (int t = 0; t < 9; ++t) a[t] = breduce_sum(part[t], red) * (1.f / 512.f);
  float mx = a[0];
#pragma unroll
  for (int t = 1; t < 9; ++t) mx = fmaxf(mx, a[t]);
  float sum = 0.f;
#pragma unroll
  for (int t = 0; t < 9; ++t) { a[t] = expf(a[t] - mx); sum += a[t]; }
  if (tid == 0) {
    float inv = 1.f / sum;
#pragma unroll
    for (int t = 0; t < 9; ++t) a9s[t] = a[t] * inv;
  }
  __syncthreads();
  float2 acc = {0.f, 0.f};
#pragma unroll
  for (int u = 0; u < 3; ++u) {
    int yy = ny + u - 1;
#pragma unroll
    for (int v = 0; v < 3; ++v) {
      int xx = nx + v - 1;
      if ((unsigned)yy < 32u && (unsigned)xx < 32u) {
        float w = a9s[u * 3 + v];
        float2 ov = *(const float2*)&orlt[(yy * 32 + xx) * 512 + c2];
        acc.x += w * ov.x;
        acc.y += w * ov.y;
      }
    }
  }
  int kk = 512 + (n >> 1);
  int pos0 = ((n & 1) << 9) + c2;
  Zt[(size_t)pos0 * 1024 + kk] = f2bf(acc.x);
  Zt[(size_t)(pos0 + 1) * 1024 + kk] = f2bf(acc.y);
}

// ---------------- K-split bf16 MFMA GEMM: 2 halves -> 2 fp32 partials -------
__global__ __launch_bounds__(256) void mfma_gemm_ks(const ushort* __restrict__ A,
                                                    const ushort* __restrict__ Bt,
                                                    float* __restrict__ Cp,
                                                    int N) {
  const int KF = 1024;
  int tid = threadIdx.x;
  int wv = tid >> 6, lane = tid & 63;
  int quad = lane >> 4, m16 = lane & 15;
  int nb = blockIdx.x * 64, mb = blockIdx.y * 64;
  int kh = blockIdx.z;
  const ushort* Ap = A + (size_t)(mb + wv * 16 + m16) * KF + kh * 512 + quad * 8;
  const ushort* Bp = Bt + (size_t)(nb + m16) * KF + kh * 512 + quad * 8;
  f32x4 ac0 = {0.f, 0.f, 0.f, 0.f}, ac1 = ac0, ac2 = ac0, ac3 = ac0;
#pragma unroll 2
  for (int k0 = 0; k0 < 512; k0 += 32) {
    bf16x8 af = *(const bf16x8*)(Ap + k0);
    bf16x8 b0 = *(const bf16x8*)(Bp + k0);
    bf16x8 b1 = *(const bf16x8*)(Bp + (size_t)16 * KF + k0);
    bf16x8 b2 = *(const bf16x8*)(Bp + (size_t)32 * KF + k0);
    bf16x8 b3 = *(const bf16x8*)(Bp + (size_t)48 * KF + k0);
    ac0 = __builtin_amdgcn_mfma_f32_16x16x32_bf16(af, b0, ac0, 0, 0, 0);
    ac1 = __builtin_amdgcn_mfma_f32_16x16x32_bf16(af, b1, ac1, 0, 0, 0);
    ac2 = __builtin_amdgcn_mfma_f32_16x16x32_bf16(af, b2, ac2, 0, 0, 0);
    ac3 = __builtin_amdgcn_mfma_f32_16x16x32_bf16(af, b3, ac3, 0, 0, 0);
  }
  int row = mb + wv * 16 + quad * 4;
  float* C = Cp + (size_t)kh * 524288;
  f32x4 accs[4] = {ac0, ac1, ac2, ac3};
#pragma unroll
  for (int nt = 0; nt < 4; ++nt)
#pragma unroll
    for (int r = 0; r < 4; ++r)
      C[(size_t)(row + r) * N + nb + nt * 16 + m16] = accs[nt][r];
}

// ---------------- InstanceNorm + LeakyReLU (sum 2 partials) -> Zt2 bf16 -----
__global__ __launch_bounds__(256) void norm_down2(const float* __restrict__ ra,
                                                  ushort* __restrict__ Zt2) {
  __shared__ float red[8];
  int c = blockIdx.x, tid = threadIdx.x;
  float v[4];
  float s = 0.f, ss = 0.f;
#pragma unroll
  for (int r = 0; r < 4; ++r) {
    int i = c * 1024 + tid + r * 256;
    v[r] = ra[i] + ra[524288 + i];
    s += v[r];
    ss += v[r] * v[r];
  }
  breduce2(s, ss, red);
  float mean = s * (1.f / 1024.f);
  float var = ss * (1.f / 1024.f) - mean * mean;
  float inv = rsqrtf(var + EPSN);
#pragma unroll
  for (int r = 0; r < 4; ++r) {
    float t = (v[r] - mean) * inv;
    t = t >= 0.f ? t : 0.2f * t;
    Zt2[(size_t)(tid + r * 256) * 1024 + c] = f2bf(t);
  }
}

// ---------------- final InstanceNorm + LeakyReLU (sum 2 partials) -----------
__global__ __launch_bounds__(256) void norm_leaky2(const float* __restrict__ ra,
                                                   float* __restrict__ out) {
  __shared__ float red[8];
  int c = blockIdx.x, tid = threadIdx.x;
  float v[4];
  float s = 0.f, ss = 0.f;
#pragma unroll
  for (int r = 0; r < 4; ++r) {
    int i = c * 1024 + tid + r * 256;
    v[r] = ra[i] + ra[524288 + i];
    s += v[r];
    ss += v[r] * v[r];
  }
  breduce2(s, ss, red);
  float mean = s * (1.f / 1024.f);
  float var = ss * (1.f / 1024.f) - mean * mean;
  float inv = rsqrtf(var + EPSN);
#pragma unroll
  for (int r = 0; r < 4; ++r) {
    float t = (v[r] - mean) * inv;
    out[c * 1024 + tid + r * 256] = t >= 0.f ? t : 0.2f * t;
  }
}

// ---------------- host launch ------------------------------------------------
extern "C" void kernel_launch(void* const* d_in, const int* in_sizes, int n_in,
                              void* d_out, int out_size, void* d_ws, size_t ws_size,
                              hipStream_t stream) {
  const float* x = (const float*)d_in[0];
  const float* gus = (const float*)d_in[1];
  const float* w3 = (const float*)d_in[2];
  const float* b3 = (const float*)d_in[3];
  const float* w5 = (const float*)d_in[4];
  const float* b5 = (const float*)d_in[5];
  const float* w7 = (const float*)d_in[6];
  const float* b7 = (const float*)d_in[7];
  const float* wfc = (const float*)d_in[8];
  const float* bfc = (const float*)d_in[9];
  const float* w0 = (const float*)d_in[10];
  const float* b0 = (const float*)d_in[11];
  const float* w1 = (const float*)d_in[12];
  const float* b1 = (const float*)d_in[13];
  const float* w2 = (const float*)d_in[14];
  const float* b2 = (const float*)d_in[15];
  const float* wdown = (const float*)d_in[16];
  const float* wfuse = (const float*)d_in[17];

  float* ws = (float*)d_ws;
  float* feas = ws;                      // 1572864 (dead after blend_fc)
  float* rawP = feas + 524288;           // 2x524288 fl partials
  float* bmean = ws + 1572864;           // 1536
  float* res = bmean + 1536;             // 524288
  float* Zt2f = res + 524288;            // 524288 fl
  ushort* Zt2 = (ushort*)Zt2f;
  float* T = Zt2f + 524288;              // 2097152
  float* Apart = T;                      // 32x65536 fl (dead before T written)
  ushort* Zt = (ushort*)T;               // (written after tcomb2)
  float* orlt = T + 2097152;             // 524288
  float* sigt = orlt + 524288;           // 524288
  ushort* orlT = (ushort*)(sigt + 524288);        // 262144 fl
  ushort* attnT = (ushort*)(sigt + 786432);       // 32768 fl
  ushort* gus_bf = (ushort*)(sigt + 819200);      // 524288 fl
  ushort* wdown_bf = (ushort*)(sigt + 1343488);   // 262144 fl
  ushort* wfuse_bf = (ushort*)(sigt + 1605632);   // 262144 fl
  ushort* resd = (ushort*)(sigt + 1867776);       // 1048576 fl

  pre_kernel<<<2304, 256, 0, stream>>>(gus, wdown, wfuse, gus_bf, wdown_bf,
                                       wfuse_bf, resd);
  sk_all5<<<256, 256, 0, stream>>>(x, w3, b3, w5, b5, w7, b7, feas, bmean);
  blend_fc<<<dim3(32, 16), 256, 0, stream>>>(feas, bmean, wfc, bfc, w0, b0, w1,
                                             b1, w2, b2, res, Zt2, resd);
  gram_part2<<<dim3(4, 4, 32), 256, 0, stream>>>(res, Apart);
  attn_soft3<<<256, 256, 0, stream>>>(Apart, attnT);
  mfma_tconv<<<dim3(8, 4, 16), 256, 0, stream>>>(attnT, resd, T);
  tcomb2<<<dim3(32, 16), 256, 0, stream>>>(T, orlt, sigt, orlT);
  gus_csa<<<1152, 256, 0, stream>>>(gus_bf, orlT, sigt, orlt, Zt);
  mfma_gemm_ks<<<dim3(16, 8, 2), 256, 0, stream>>>(wdown_bf, Zt, rawP, 1024);
  norm_down2<<<512, 256, 0, stream>>>(rawP, Zt2);
  mfma_gemm_ks<<<dim3(16, 8, 2), 256, 0, stream>>>(wfuse_bf, Zt2, rawP, 1024);
  norm_leaky2<<<512, 256, 0, stream>>>(rawP, (float*)d_out);
}

// Round 14
// 259.913 us; speedup vs baseline: 3.9546x; 1.0001x over previous
//
#include <hip/hip_runtime.h>
#include <math.h>

#define EPSN 1e-5f

typedef __attribute__((ext_vector_type(8))) short bf16x8;
typedef __attribute__((ext_vector_type(4))) float f32x4;

__device__ __forceinline__ ushort f2bf(float f) {
  unsigned u = __float_as_uint(f);
  unsigned r = (u + 0x7fff + ((u >> 16) & 1)) >> 16;
  return (ushort)r;
}

// ---------------- block-wide reductions (blockDim.x == 256, 4 waves) --------
__device__ __forceinline__ void breduce2(float& a, float& b, float* lds) {
#pragma unroll
  for (int o = 32; o > 0; o >>= 1) {
    a += __shfl_down(a, o);
    b += __shfl_down(b, o);
  }
  int lane = threadIdx.x & 63, wid = threadIdx.x >> 6;
  __syncthreads();
  if (lane == 0) { lds[wid] = a; lds[4 + wid] = b; }
  __syncthreads();
  a = lds[0] + lds[1] + lds[2] + lds[3];
  b = lds[4] + lds[5] + lds[6] + lds[7];
}

__device__ __forceinline__ float breduce_sum(float v, float* lds) {
#pragma unroll
  for (int o = 32; o > 0; o >>= 1) v += __shfl_down(v, o);
  int lane = threadIdx.x & 63, wid = threadIdx.x >> 6;
  __syncthreads();
  if (lane == 0) lds[wid] = v;
  __syncthreads();
  return lds[0] + lds[1] + lds[2] + lds[3];
}

__device__ __forceinline__ float breduce_max(float v, float* lds) {
#pragma unroll
  for (int o = 32; o > 0; o >>= 1) v = fmaxf(v, __shfl_down(v, o));
  int lane = threadIdx.x & 63, wid = threadIdx.x >> 6;
  __syncthreads();
  if (lane == 0) lds[wid] = v;
  __syncthreads();
  return fmaxf(fmaxf(lds[0], lds[1]), fmaxf(lds[2], lds[3]));
}

// ---------------- pre: bf16 converts + resd memset --------------------------
__global__ void pre_kernel(const float* __restrict__ gus,
                           const float* __restrict__ wdown,
                           const float* __restrict__ wfuse,
                           ushort* __restrict__ gus_bf,
                           ushort* __restrict__ wdown_bf,
                           ushort* __restrict__ wfuse_bf,
                           ushort* __restrict__ resd) {
  int bid = blockIdx.x, tid = threadIdx.x;
  if (bid < 2048) {
    int i = bid * 1024 + tid * 4;
    const float* src; ushort* dst; int off;
    if (i < 1048576) { src = gus; dst = gus_bf; off = i; }
    else if (i < 1572864) { src = wdown; dst = wdown_bf; off = i - 1048576; }
    else { src = wfuse; dst = wfuse_bf; off = i - 1572864; }
    float4 v = *(const float4*)&src[off];
    ushort4 o = {f2bf(v.x), f2bf(v.y), f2bf(v.z), f2bf(v.w)};
    *(ushort4*)&dst[off] = o;
  } else {
    int t8 = (bid - 2048) * 256 + tid;
    uint4 z = {0u, 0u, 0u, 0u};
#pragma unroll
    for (int k = 0; k < 4; ++k) *(uint4*)&resd[(size_t)(t8 + k * 65536) * 8] = z;
  }
}

// ---------------- SKConv via MFMA: grouped conv as 16x1024xK GEMM -----------
// grid 256 = 32 groups x 8 row-slices. K packed as 43 tap-pairs x 16 ic.
// feasRaw[br][c][pos] fp32 (br: 0=k3, 1=k5, 2=k7); bias omitted (IN cancels it).
__global__ __launch_bounds__(256) void sk_mfma(const float* __restrict__ x,
                                               const float* __restrict__ w3,
                                               const float* __restrict__ w5,
                                               const float* __restrict__ w7,
                                               float* __restrict__ feasRaw) {
  __shared__ ushort xg[10 * 38 * 24];   // [lr][cx][ic pad24] bf16, 18.2 KB
  __shared__ ushort Apk[43 * 32 * 16];  // packed A-fragments, 43 KB
  int bid = blockIdx.x, tid = threadIdx.x;
  int g = bid >> 3, sl = bid & 7, y0 = sl * 4;
  for (int i = tid; i < 4560; i += 256) ((uint*)xg)[i] = 0u;
  // pack A: idx = ((p*4+quad)*16+m16)*8 + j ; k=quad*8+j -> (tp=k>>4, ic=k&15)
  for (int i = tid; i < 22016; i += 256) {
    int p = i >> 9;
    int r5 = i & 511;
    int quad = r5 >> 7, m16 = (r5 >> 3) & 15, j = i & 7;
    int k = quad * 8 + j, tp = k >> 4, ic = k & 15;
    float val = 0.f;
    if (p < 25) {
      int t = 2 * p + tp;
      if (t < 49) val = w7[(size_t)(g * 16 + m16) * 784 + ic * 49 + t];
    } else if (p < 38) {
      int t = 2 * (p - 25) + tp;
      if (t < 25) val = w5[(size_t)(g * 16 + m16) * 400 + ic * 25 + t];
    } else {
      int t = 2 * (p - 38) + tp;
      if (t < 9) val = w3[(size_t)(g * 16 + m16) * 144 + ic * 9 + t];
    }
    Apk[i] = f2bf(val);
  }
  __syncthreads();
  // fill xg (coalesced in x): [lr][ic][xcol]
  for (int i = tid; i < 5120; i += 256) {
    int lr = i >> 9, ic = (i >> 5) & 15, xc = i & 31;
    int y = y0 + lr - 3;
    if ((unsigned)y < 32u)
      xg[(lr * 38 + xc + 3) * 24 + ic] =
          f2bf(x[(size_t)(g * 16 + ic) * 1024 + y * 32 + xc]);
  }
  __syncthreads();
  int wv = tid >> 6, lane = tid & 63, quad = lane >> 4, m16 = lane & 15;
  int qh = (quad & 1) * 8, tp = quad >> 1;
  f32x4 acc[2][3] = {};
  // k7 (br 2): pairs 0..24
  for (int p = 0; p < 25; ++p) {
    bf16x8 af = *(const bf16x8*)&Apk[(p * 4 + quad) * 128 + m16 * 8];
    int t = 2 * p + tp;
    if (t > 48) t = 48;
    int ky = t / 7, kx = t - ky * 7;
#pragma unroll
    for (int ti = 0; ti < 2; ++ti) {
      int T = wv + ti * 4, tl = T >> 1, x0c = (T & 1) * 16;
      bf16x8 bf = *(const bf16x8*)&xg[((tl + ky) * 38 + x0c + m16 + kx) * 24 + qh];
      acc[ti][2] = __builtin_amdgcn_mfma_f32_16x16x32_bf16(af, bf, acc[ti][2], 0, 0, 0);
    }
  }
  // k5 (br 1): pairs 25..37
  for (int p = 0; p < 13; ++p) {
    bf16x8 af = *(const bf16x8*)&Apk[((p + 25) * 4 + quad) * 128 + m16 * 8];
    int t = 2 * p + tp;
    if (t > 24) t = 24;
    int ky = t / 5, kx = t - ky * 5;
#pragma unroll
    for (int ti = 0; ti < 2; ++ti) {
      int T = wv + ti * 4, tl = T >> 1, x0c = (T & 1) * 16;
      bf16x8 bf =
          *(const bf16x8*)&xg[((tl + ky + 1) * 38 + x0c + m16 + kx + 1) * 24 + qh];
      acc[ti][1] = __builtin_amdgcn_mfma_f32_16x16x32_bf16(af, bf, acc[ti][1], 0, 0, 0);
    }
  }
  // k3 (br 0): pairs 38..42
  for (int p = 0; p < 5; ++p) {
    bf16x8 af = *(const bf16x8*)&Apk[((p + 38) * 4 + quad) * 128 + m16 * 8];
    int t = 2 * p + tp;
    if (t > 8) t = 8;
    int ky = t / 3, kx = t - ky * 3;
#pragma unroll
    for (int ti = 0; ti < 2; ++ti) {
      int T = wv + ti * 4, tl = T >> 1, x0c = (T & 1) * 16;
      bf16x8 bf =
          *(const bf16x8*)&xg[((tl + ky + 2) * 38 + x0c + m16 + kx + 2) * 24 + qh];
      acc[ti][0] = __builtin_amdgcn_mfma_f32_16x16x32_bf16(af, bf, acc[ti][0], 0, 0, 0);
    }
  }
  int cb = g * 16 + quad * 4;
#pragma unroll
  for (int ti = 0; ti < 2; ++ti) {
    int T = wv + ti * 4, tl = T >> 1, x0c = (T & 1) * 16;
    int pos = (y0 + tl) * 32 + x0c + m16;
#pragma unroll
    for (int br = 0; br < 3; ++br)
#pragma unroll
      for (int r = 0; r < 4; ++r)
        feasRaw[(size_t)(br * 512 + cb + r) * 1024 + pos] = acc[ti][br][r];
  }
}

// ---------------- InstanceNorm + ReLU + branch-mean from raw conv -----------
__global__ __launch_bounds__(256) void sk_norm(const float* __restrict__ raw,
                                               float* __restrict__ feas,
                                               float* __restrict__ bmean) {
  __shared__ float red[8];
  int mc = blockIdx.x, tid = threadIdx.x;
  float v[4];
  float s = 0.f, ss = 0.f;
#pragma unroll
  for (int r = 0; r < 4; ++r) {
    v[r] = raw[(size_t)mc * 1024 + tid + r * 256];
    s += v[r];
    ss += v[r] * v[r];
  }
  breduce2(s, ss, red);
  float mean = s * (1.f / 1024.f);
  float var = ss * (1.f / 1024.f) - mean * mean;
  float inv = rsqrtf(var + EPSN);
  float rs = 0.f;
#pragma unroll
  for (int r = 0; r < 4; ++r) {
    float t = (v[r] - mean) * inv;
    t = t > 0.f ? t : 0.f;
    feas[(size_t)mc * 1024 + tid + r * 256] = t;
    rs += t;
  }
  float tot = breduce_sum(rs, red);
  if (tid == 0) bmean[mc] = tot * (1.f / 1024.f);
}

// ---------------- blend + FC-attention; writes res, Zt2 res-half, resd ------
__global__ __launch_bounds__(256) void blend_fc(
    const float* __restrict__ feas, const float* __restrict__ bmean,
    const float* __restrict__ wfc, const float* __restrict__ bfc,
    const float* __restrict__ w0, const float* __restrict__ b0,
    const float* __restrict__ w1, const float* __restrict__ b1,
    const float* __restrict__ w2, const float* __restrict__ b2,
    float* __restrict__ res, ushort* __restrict__ Zt2,
    ushort* __restrict__ resd) {
  __shared__ float sfea[512];
  __shared__ float zpart[8][32];
  __shared__ float zz[32];
  __shared__ float lv[3][32];
  __shared__ float attb[3][32];
  __shared__ float tile[32][33];
  int tid = threadIdx.x;
  int pb = blockIdx.x * 32, cb = blockIdx.y * 32;
  for (int c = tid; c < 512; c += 256)
    sfea[c] = bmean[c] + bmean[512 + c] + bmean[1024 + c];
  __syncthreads();
  {
    int j = tid & 31, seg = tid >> 5;
    float p = 0.f;
    for (int c = seg * 64; c < seg * 64 + 64; ++c) p += sfea[c] * wfc[j * 512 + c];
    zpart[seg][j] = p;
  }
  __syncthreads();
  if (tid < 32) {
    float d = bfc[tid];
#pragma unroll
    for (int s = 0; s < 8; ++s) d += zpart[s][tid];
    zz[tid] = d;
  }
  __syncthreads();
  if (tid < 96) {
    int m = tid >> 5, cl = tid & 31;
    const float* wm = (m == 0) ? w0 : (m == 1) ? w1 : w2;
    const float* bm = (m == 0) ? b0 : (m == 1) ? b1 : b2;
    float l = bm[cb + cl];
#pragma unroll
    for (int j = 0; j < 32; ++j) l += zz[j] * wm[(cb + cl) * 32 + j];
    lv[m][cl] = l;
  }
  __syncthreads();
  if (tid < 32) {
    float l0 = lv[0][tid], l1 = lv[1][tid], l2 = lv[2][tid];
    float mx = fmaxf(l0, fmaxf(l1, l2));
    float e0 = expf(l0 - mx), e1 = expf(l1 - mx), e2 = expf(l2 - mx);
    float inv = 1.f / (e0 + e1 + e2);
    attb[0][tid] = e0 * inv; attb[1][tid] = e1 * inv; attb[2][tid] = e2 * inv;
  }
  __syncthreads();
  int tx = tid & 31, ty = tid >> 5;
  int pos = pb + tx;
  int yy = pos >> 5, xx = pos & 31;
  int ki0 = (yy + 1) & 1, pi0 = (yy + 1 - ki0) >> 1;
  int kj0 = (xx + 1) & 1, pj0 = (xx + 1 - kj0) >> 1;
#pragma unroll
  for (int r = 0; r < 4; ++r) {
    int cl = ty + r * 8;
    int c = cb + cl;
    float v = feas[c * 1024 + pos] * attb[0][cl] +
              feas[(512 + c) * 1024 + pos] * attb[1][cl] +
              feas[(1024 + c) * 1024 + pos] * attb[2][cl];
    res[c * 1024 + pos] = v;
    tile[cl][tx] = v;
    ushort bv16 = f2bf(v);
#pragma unroll
    for (int ai = 0; ai < 2; ++ai) {
      int ki = ki0 + 2 * ai, pi = pi0 - ai;
      if ((unsigned)pi >= 16u) continue;
#pragma unroll
      for (int aj = 0; aj < 2; ++aj) {
        int kj = kj0 + 2 * aj, pj = pj0 - aj;
        if ((unsigned)pj >= 16u) continue;
        resd[((size_t)(ki * 4 + kj) << 17) + (size_t)c * 256 + pi * 16 + pj] = bv16;
      }
    }
  }
  __syncthreads();
#pragma unroll
  for (int r = 0; r < 4; ++r) {
    int pl = ty + r * 8;
    Zt2[(size_t)(pb + pl) * 1024 + 512 + cb + tx] = f2bf(tile[tx][pl]);
  }
}

// ---------------- Gram split-K partials, 16-ch chunks (512 blocks) ----------
__global__ __launch_bounds__(256) void gram_part2(const float* __restrict__ res,
                                                  float* __restrict__ Apart) {
  __shared__ float ch[4][324];
  int tid = threadIdx.x;
  int qb = blockIdx.x * 64, pb = blockIdx.y * 64;
  int kc = blockIdx.z;
  int tx = tid & 15, ty = tid >> 4;
  for (int i = tid; i < 4 * 324; i += 256) ((float*)ch)[i] = 0.f;
  int pi = (pb + ty * 4) >> 4, pj = (pb + ty * 4) & 15;
  int qi = (qb + tx * 4) >> 4, qj = (qb + tx * 4) & 15;
  int lane = tid & 63, wv = tid >> 6;
  int sr = lane >> 2, sc = (lane & 3) * 4;
  float acc[4][4] = {};
  for (int c0 = kc * 16; c0 < kc * 16 + 16; c0 += 4) {
    __syncthreads();
    {
      const float* src = res + (size_t)(c0 + wv) * 1024 + (2 * sr) * 32 + 2 * sc;
      float4 r0a = *(const float4*)src;
      float4 r0b = *(const float4*)(src + 4);
      float4 r1a = *(const float4*)(src + 32);
      float4 r1b = *(const float4*)(src + 36);
      float* dst = &ch[wv][(sr + 1) * 18 + sc + 1];
      dst[0] = 0.25f * (r0a.x + r0a.y + r1a.x + r1a.y);
      dst[1] = 0.25f * (r0a.z + r0a.w + r1a.z + r1a.w);
      dst[2] = 0.25f * (r0b.x + r0b.y + r1b.x + r1b.y);
      dst[3] = 0.25f * (r0b.z + r0b.w + r1b.z + r1b.w);
    }
    __syncthreads();
#pragma unroll
    for (int cc = 0; cc < 4; ++cc) {
      float ps[3][6], qs[3][6];
#pragma unroll
      for (int u = 0; u < 3; ++u) {
        const float* pr = &ch[cc][(pi + u) * 18 + pj];
        const float* qr = &ch[cc][(qi + u) * 18 + qj];
#pragma unroll
        for (int t = 0; t < 6; ++t) { ps[u][t] = pr[t]; qs[u][t] = qr[t]; }
      }
#pragma unroll
      for (int u = 0; u < 3; ++u)
#pragma unroll
        for (int v = 0; v < 3; ++v)
#pragma unroll
          for (int i = 0; i < 4; ++i)
#pragma unroll
            for (int j = 0; j < 4; ++j)
              acc[i][j] += ps[u][v + i] * qs[u][v + j];
    }
  }
#pragma unroll
  for (int i = 0; i < 4; ++i) {
    float4 o4 = {acc[i][0], acc[i][1], acc[i][2], acc[i][3]};
    *(float4*)&Apart[(size_t)kc * 65536 + (pb + ty * 4 + i) * 256 + qb + tx * 4] = o4;
  }
}

// ---------------- softmax + inline diag norm -> attnT bf16 ------------------
__global__ __launch_bounds__(256) void attn_soft3(const float* __restrict__ Apart,
                                                  ushort* __restrict__ attnT) {
  __shared__ float red[8];
  int q = blockIdx.x, t = threadIdx.x;
  float d = 0.f, s = 0.f;
#pragma unroll
  for (int k = 0; k < 32; ++k) {
    d += Apart[(size_t)k * 65536 + t * 257];
    s += Apart[(size_t)k * 65536 + q * 256 + t];
  }
  float invn = 10.f / fmaxf(sqrtf(fmaxf(d, 0.f)), 1e-4f);
  float v = s * invn;
  float mx = breduce_max(v, red);
  float e = expf(v - mx);
  float sm = breduce_sum(e, red);
  attnT[q * 256 + t] = f2bf(e / sm);
}

// ---------------- tconv: 16-batch bf16 MFMA GEMM ----------------------------
__global__ __launch_bounds__(256) void mfma_tconv(const ushort* __restrict__ attnT,
                                                  const ushort* __restrict__ resd,
                                                  float* __restrict__ T) {
  int tid = threadIdx.x;
  int wv = tid >> 6, lane = tid & 63;
  int quad = lane >> 4, m16 = lane & 15;
  int nb = blockIdx.x * 64, qb = blockIdx.y * 64;
  int b = blockIdx.z;
  const ushort* Ap = attnT + (size_t)(qb + wv * 16 + m16) * 256 + quad * 8;
  const ushort* Bp = resd + (size_t)b * 131072 + (size_t)(nb + m16) * 256 + quad * 8;
  f32x4 ac0 = {0.f, 0.f, 0.f, 0.f}, ac1 = ac0, ac2 = ac0, ac3 = ac0;
#pragma unroll 2
  for (int k0 = 0; k0 < 256; k0 += 32) {
    bf16x8 af = *(const bf16x8*)(Ap + k0);
    bf16x8 b0 = *(const bf16x8*)(Bp + k0);
    bf16x8 b1 = *(const bf16x8*)(Bp + 16 * 256 + k0);
    bf16x8 b2 = *(const bf16x8*)(Bp + 32 * 256 + k0);
    bf16x8 b3 = *(const bf16x8*)(Bp + 48 * 256 + k0);
    ac0 = __builtin_amdgcn_mfma_f32_16x16x32_bf16(af, b0, ac0, 0, 0, 0);
    ac1 = __builtin_amdgcn_mfma_f32_16x16x32_bf16(af, b1, ac1, 0, 0, 0);
    ac2 = __builtin_amdgcn_mfma_f32_16x16x32_bf16(af, b2, ac2, 0, 0, 0);
    ac3 = __builtin_amdgcn_mfma_f32_16x16x32_bf16(af, b3, ac3, 0, 0, 0);
  }
  int row = qb + wv * 16 + quad * 4;
  float* Cb = T + (size_t)b * 131072;
  f32x4 accs[4] = {ac0, ac1, ac2, ac3};
#pragma unroll
  for (int nt = 0; nt < 4; ++nt)
#pragma unroll
    for (int r = 0; r < 4; ++r)
      Cb[(size_t)(row + r) * 512 + nb + nt * 16 + m16] = accs[nt][r];
}

// ---------------- combine taps -> orlt, sigt, orlT bf16 (tiled) -------------
__global__ __launch_bounds__(256) void tcomb2(const float* __restrict__ T,
                                              float* __restrict__ orlt,
                                              float* __restrict__ sigt,
                                              ushort* __restrict__ orlT) {
  __shared__ float tl[32][33];
  int nb = blockIdx.x * 32, cb = blockIdx.y * 32;
  int tx = threadIdx.x & 31, ty = threadIdx.x >> 5;
#pragma unroll
  for (int r = 0; r < 4; ++r) {
    int nl = ty + r * 8;
    int n = nb + nl, c = cb + tx;
    int y = n >> 5, x = n & 31;
    int i0 = (y + 1) >> 1, ki0 = (y + 1) & 1;
    int j0 = (x + 1) >> 1, kj0 = (x + 1) & 1;
    float sum = 0.f;
#pragma unroll
    for (int iy = 0; iy < 2; ++iy) {
      int i = i0 - iy, ki = ki0 + 2 * iy;
      if ((unsigned)i >= 16u) continue;
#pragma unroll
      for (int ix = 0; ix < 2; ++ix) {
        int j = j0 - ix, kj = kj0 + 2 * ix;
        if ((unsigned)j >= 16u) continue;
        sum += T[((ki * 4 + kj) * 256 + i * 16 + j) * 512 + c];
      }
    }
    float v = sum * 0.25f;
    orlt[n * 512 + c] = v;
    sigt[n * 512 + c] = 1.f / (1.f + expf(-v));
    tl[nl][tx] = v;
  }
  __syncthreads();
#pragma unroll
  for (int r = 0; r < 4; ++r) {
    int cl = ty + r * 8;
    orlT[(size_t)(cb + cl) * 1024 + nb + tx] = f2bf(tl[tx][cl]);
  }
}

// ---------------- merged: gus GEMM (blocks 0..127) + CSA (128..1151) --------
__global__ __launch_bounds__(256) void gus_csa(
    const ushort* __restrict__ gus_bf, const ushort* __restrict__ orlT,
    const float* __restrict__ sigt, const float* __restrict__ orlt,
    ushort* __restrict__ Zt) {
  __shared__ float red[8];
  __shared__ float a9s[9];
  int tid = threadIdx.x;
  if (blockIdx.x < 128) {
    const int K = 1024;
    int wv = tid >> 6, lane = tid & 63;
    int quad = lane >> 4, m16 = lane & 15;
    int nb = (blockIdx.x & 7) * 64, mb = (blockIdx.x >> 3) * 64;
    const ushort* Ap = gus_bf + (size_t)(mb + wv * 16 + m16) * K + quad * 8;
    const ushort* Bp = orlT + (size_t)(nb + m16) * K + quad * 8;
    f32x4 ac0 = {0.f, 0.f, 0.f, 0.f}, ac1 = ac0, ac2 = ac0, ac3 = ac0;
#pragma unroll 2
    for (int k0 = 0; k0 < K; k0 += 32) {
      bf16x8 af = *(const bf16x8*)(Ap + k0);
      bf16x8 b0 = *(const bf16x8*)(Bp + k0);
      bf16x8 b1 = *(const bf16x8*)(Bp + (size_t)16 * K + k0);
      bf16x8 b2 = *(const bf16x8*)(Bp + (size_t)32 * K + k0);
      bf16x8 b3 = *(const bf16x8*)(Bp + (size_t)48 * K + k0);
      ac0 = __builtin_amdgcn_mfma_f32_16x16x32_bf16(af, b0, ac0, 0, 0, 0);
      ac1 = __builtin_amdgcn_mfma_f32_16x16x32_bf16(af, b1, ac1, 0, 0, 0);
      ac2 = __builtin_amdgcn_mfma_f32_16x16x32_bf16(af, b2, ac2, 0, 0, 0);
      ac3 = __builtin_amdgcn_mfma_f32_16x16x32_bf16(af, b3, ac3, 0, 0, 0);
    }
    int row = mb + wv * 16 + quad * 4;
    f32x4 accs[4] = {ac0, ac1, ac2, ac3};
#pragma unroll
    for (int nt = 0; nt < 4; ++nt) {
      int c = nb + nt * 16 + m16;
#pragma unroll
      for (int r = 0; r < 4; ++r) {
        int p = row + r;
        int pos = ((p & 1) << 9) + c;
        int kk = p >> 1;
        Zt[(size_t)pos * 1024 + kk] = f2bf(accs[nt][r]);
      }
    }
    return;
  }
  int n = blockIdx.x - 128;
  int ny = n >> 5, nx = n & 31;
  int c2 = tid * 2;
  float2 ctr = *(const float2*)&sigt[n * 512 + c2];
  float part[9];
#pragma unroll
  for (int u = 0; u < 3; ++u) {
    int yy = ny + u - 1;
#pragma unroll
    for (int v = 0; v < 3; ++v) {
      int xx = nx + v - 1;
      float2 nb2 = {0.f, 0.f};
      if ((unsigned)yy < 32u && (unsigned)xx < 32u)
        nb2 = *(const float2*)&sigt[(yy * 32 + xx) * 512 + c2];
      part[u * 3 + v] = ctr.x * nb2.x + ctr.y * nb2.y;
    }
  }
  float a[9];
#pragma unroll
  for (int t = 0; t < 9; ++t) a[t] = breduce_sum(part[t], red) * (1.f / 512.f);
  float mx = a[0];
#pragma unroll
  for (int t = 1; t < 9; ++t) mx = fmaxf(mx, a[t]);
  float sum = 0.f;
#pragma unroll
  for (int t = 0; t < 9; ++t) { a[t] = expf(a[t] - mx); sum += a[t]; }
  if (tid == 0) {
    float inv = 1.f / sum;
#pragma unroll
    for (int t = 0; t < 9; ++t) a9s[t] = a[t] * inv;
  }
  __syncthreads();
  float2 acc = {0.f, 0.f};
#pragma unroll
  for (int u = 0; u < 3; ++u) {
    int yy = ny + u - 1;
#pragma unroll
    for (int v = 0; v < 3; ++v) {
      int xx = nx + v - 1;
      if ((unsigned)yy < 32u && (unsigned)xx < 32u) {
        float w = a9s[u * 3 + v];
        float2 ov = *(const float2*)&orlt[(yy * 32 + xx) * 512 + c2];
        acc.x += w * ov.x;
        acc.y += w * ov.y;
      }
    }
  }
  int kk = 512 + (n >> 1);
  int pos0 = ((n & 1) << 9) + c2;
  Zt[(size_t)pos0 * 1024 + kk] = f2bf(acc.x);
  Zt[(size_t)(pos0 + 1) * 1024 + kk] = f2bf(acc.y);
}

// ---------------- K-split bf16 MFMA GEMM: 2 halves -> 2 fp32 partials -------
__global__ __launch_bounds__(256) void mfma_gemm_ks(const ushort* __restrict__ A,
                                                    const ushort* __restrict__ Bt,
                                                    float* __restrict__ Cp,
                                                    int N) {
  const int KF = 1024;
  int tid = threadIdx.x;
  int wv = tid >> 6, lane = tid & 63;
  int quad = lane >> 4, m16 = lane & 15;
  int nb = blockIdx.x * 64, mb = blockIdx.y * 64;
  int kh = blockIdx.z;
  const ushort* Ap = A + (size_t)(mb + wv * 16 + m16) * KF + kh * 512 + quad * 8;
  const ushort* Bp = Bt + (size_t)(nb + m16) * KF + kh * 512 + quad * 8;
  f32x4 ac0 = {0.f, 0.f, 0.f, 0.f}, ac1 = ac0, ac2 = ac0, ac3 = ac0;
#pragma unroll 2
  for (int k0 = 0; k0 < 512; k0 += 32) {
    bf16x8 af = *(const bf16x8*)(Ap + k0);
    bf16x8 b0 = *(const bf16x8*)(Bp + k0);
    bf16x8 b1 = *(const bf16x8*)(Bp + (size_t)16 * KF + k0);
    bf16x8 b2 = *(const bf16x8*)(Bp + (size_t)32 * KF + k0);
    bf16x8 b3 = *(const bf16x8*)(Bp + (size_t)48 * KF + k0);
    ac0 = __builtin_amdgcn_mfma_f32_16x16x32_bf16(af, b0, ac0, 0, 0, 0);
    ac1 = __builtin_amdgcn_mfma_f32_16x16x32_bf16(af, b1, ac1, 0, 0, 0);
    ac2 = __builtin_amdgcn_mfma_f32_16x16x32_bf16(af, b2, ac2, 0, 0, 0);
    ac3 = __builtin_amdgcn_mfma_f32_16x16x32_bf16(af, b3, ac3, 0, 0, 0);
  }
  int row = mb + wv * 16 + quad * 4;
  float* C = Cp + (size_t)kh * 524288;
  f32x4 accs[4] = {ac0, ac1, ac2, ac3};
#pragma unroll
  for (int nt = 0; nt < 4; ++nt)
#pragma unroll
    for (int r = 0; r < 4; ++r)
      C[(size_t)(row + r) * N + nb + nt * 16 + m16] = accs[nt][r];
}

// ---------------- InstanceNorm + LeakyReLU (sum 2 partials) -> Zt2 bf16 -----
__global__ __launch_bounds__(256) void norm_down2(const float* __restrict__ ra,
                                                  ushort* __restrict__ Zt2) {
  __shared__ float red[8];
  int c = blockIdx.x, tid = threadIdx.x;
  float v[4];
  float s = 0.f, ss = 0.f;
#pragma unroll
  for (int r = 0; r < 4; ++r) {
    int i = c * 1024 + tid + r * 256;
    v[r] = ra[i] + ra[524288 + i];
    s += v[r];
    ss += v[r] * v[r];
  }
  breduce2(s, ss, red);
  float mean = s * (1.f / 1024.f);
  float var = ss * (1.f / 1024.f) - mean * mean;
  float inv = rsqrtf(var + EPSN);
#pragma unroll
  for (int r = 0; r < 4; ++r) {
    float t = (v[r] - mean) * inv;
    t = t >= 0.f ? t : 0.2f * t;
    Zt2[(size_t)(tid + r * 256) * 1024 + c] = f2bf(t);
  }
}

// ---------------- final InstanceNorm + LeakyReLU (sum 2 partials) -----------
__global__ __launch_bounds__(256) void norm_leaky2(const float* __restrict__ ra,
                                                   float* __restrict__ out) {
  __shared__ float red[8];
  int c = blockIdx.x, tid = threadIdx.x;
  float v[4];
  float s = 0.f, ss = 0.f;
#pragma unroll
  for (int r = 0; r < 4; ++r) {
    int i = c * 1024 + tid + r * 256;
    v[r] = ra[i] + ra[524288 + i];
    s += v[r];
    ss += v[r] * v[r];
  }
  breduce2(s, ss, red);
  float mean = s * (1.f / 1024.f);
  float var = ss * (1.f / 1024.f) - mean * mean;
  float inv = rsqrtf(var + EPSN);
#pragma unroll
  for (int r = 0; r < 4; ++r) {
    float t = (v[r] - mean) * inv;
    out[c * 1024 + tid + r * 256] = t >= 0.f ? t : 0.2f * t;
  }
}

// ---------------- host launch ------------------------------------------------
extern "C" void kernel_launch(void* const* d_in, const int* in_sizes, int n_in,
                              void* d_out, int out_size, void* d_ws, size_t ws_size,
                              hipStream_t stream) {
  const float* x = (const float*)d_in[0];
  const float* gus = (const float*)d_in[1];
  const float* w3 = (const float*)d_in[2];
  const float* w5 = (const float*)d_in[4];
  const float* w7 = (const float*)d_in[6];
  const float* wfc = (const float*)d_in[8];
  const float* bfc = (const float*)d_in[9];
  const float* w0 = (const float*)d_in[10];
  const float* b0 = (const float*)d_in[11];
  const float* w1 = (const float*)d_in[12];
  const float* b1 = (const float*)d_in[13];
  const float* w2 = (const float*)d_in[14];
  const float* b2 = (const float*)d_in[15];
  const float* wdown = (const float*)d_in[16];
  const float* wfuse = (const float*)d_in[17];

  float* ws = (float*)d_ws;
  float* feas = ws;                      // 1572864 (dead after blend_fc)
  float* rawP = feas + 524288;           // 2x524288 fl partials
  float* bmean = ws + 1572864;           // 1536
  float* res = bmean + 1536;             // 524288
  float* Zt2f = res + 524288;            // 524288 fl
  ushort* Zt2 = (ushort*)Zt2f;
  float* T = Zt2f + 524288;              // 2097152
  float* feasRaw = T;                    // 1572864 fl (dead before gram)
  float* Apart = T;                      // 32x65536 fl (dead before T written)
  ushort* Zt = (ushort*)T;               // (written after tcomb2)
  float* orlt = T + 2097152;             // 524288
  float* sigt = orlt + 524288;           // 524288
  ushort* orlT = (ushort*)(sigt + 524288);        // 262144 fl
  ushort* attnT = (ushort*)(sigt + 786432);       // 32768 fl
  ushort* gus_bf = (ushort*)(sigt + 819200);      // 524288 fl
  ushort* wdown_bf = (ushort*)(sigt + 1343488);   // 262144 fl
  ushort* wfuse_bf = (ushort*)(sigt + 1605632);   // 262144 fl
  ushort* resd = (ushort*)(sigt + 1867776);       // 1048576 fl

  pre_kernel<<<2304, 256, 0, stream>>>(gus, wdown, wfuse, gus_bf, wdown_bf,
                                       wfuse_bf, resd);
  sk_mfma<<<256, 256, 0, stream>>>(x, w3, w5, w7, feasRaw);
  sk_norm<<<1536, 256, 0, stream>>>(feasRaw, feas, bmean);
  blend_fc<<<dim3(32, 16), 256, 0, stream>>>(feas, bmean, wfc, bfc, w0, b0, w1,
                                             b1, w2, b2, res, Zt2, resd);
  gram_part2<<<dim3(4, 4, 32), 256, 0, stream>>>(res, Apart);
  attn_soft3<<<256, 256, 0, stream>>>(Apart, attnT);
  mfma_tconv<<<dim3(8, 4, 16), 256, 0, stream>>>(attnT, resd, T);
  tcomb2<<<dim3(32, 16), 256, 0, stream>>>(T, orlt, sigt, orlT);
  gus_csa<<<1152, 256, 0, stream>>>(gus_bf, orlT, sigt, orlt, Zt);
  mfma_gemm_ks<<<dim3(16, 8, 2), 256, 0, stream>>>(wdown_bf, Zt, rawP, 1024);
  norm_down2<<<512, 256, 0, stream>>>(rawP, Zt2);
  mfma_gemm_ks<<<dim3(16, 8, 2), 256, 0, stream>>>(wfuse_bf, Zt2, rawP, 1024);
  norm_leaky2<<<512, 256, 0, stream>>>(rawP, (float*)d_out);
}

// Round 15
// 238.832 us; speedup vs baseline: 4.3036x; 1.0883x over previous
//
#include <hip/hip_runtime.h>
#include <math.h>

#define EPSN 1e-5f

typedef __attribute__((ext_vector_type(8))) short bf16x8;
typedef __attribute__((ext_vector_type(4))) float f32x4;

__device__ __forceinline__ ushort f2bf(float f) {
  unsigned u = __float_as_uint(f);
  unsigned r = (u + 0x7fff + ((u >> 16) & 1)) >> 16;
  return (ushort)r;
}

// ---------------- block-wide reductions (blockDim.x == 256, 4 waves) --------
__device__ __forceinline__ void breduce2(float& a, float& b, float* lds) {
#pragma unroll
  for (int o = 32; o > 0; o >>= 1) {
    a += __shfl_down(a, o);
    b += __shfl_down(b, o);
  }
  int lane = threadIdx.x & 63, wid = threadIdx.x >> 6;
  __syncthreads();
  if (lane == 0) { lds[wid] = a; lds[4 + wid] = b; }
  __syncthreads();
  a = lds[0] + lds[1] + lds[2] + lds[3];
  b = lds[4] + lds[5] + lds[6] + lds[7];
}

__device__ __forceinline__ float breduce_sum(float v, float* lds) {
#pragma unroll
  for (int o = 32; o > 0; o >>= 1) v += __shfl_down(v, o);
  int lane = threadIdx.x & 63, wid = threadIdx.x >> 6;
  __syncthreads();
  if (lane == 0) lds[wid] = v;
  __syncthreads();
  return lds[0] + lds[1] + lds[2] + lds[3];
}

__device__ __forceinline__ float breduce_max(float v, float* lds) {
#pragma unroll
  for (int o = 32; o > 0; o >>= 1) v = fmaxf(v, __shfl_down(v, o));
  int lane = threadIdx.x & 63, wid = threadIdx.x >> 6;
  __syncthreads();
  if (lane == 0) lds[wid] = v;
  __syncthreads();
  return fmaxf(fmaxf(lds[0], lds[1]), fmaxf(lds[2], lds[3]));
}

// ---------------- pre: bf16 converts + resd memset + SK weight packing ------
// blocks 0..2047: converts; 2048..2303: resd zero; 2304..5055: Apk_g pack
__global__ void pre_kernel(const float* __restrict__ gus,
                           const float* __restrict__ wdown,
                           const float* __restrict__ wfuse,
                           const float* __restrict__ w3,
                           const float* __restrict__ w5,
                           const float* __restrict__ w7,
                           ushort* __restrict__ gus_bf,
                           ushort* __restrict__ wdown_bf,
                           ushort* __restrict__ wfuse_bf,
                           ushort* __restrict__ resd,
                           ushort* __restrict__ Apk_g) {
  int bid = blockIdx.x, tid = threadIdx.x;
  if (bid < 2048) {
    int i = bid * 1024 + tid * 4;
    const float* src; ushort* dst; int off;
    if (i < 1048576) { src = gus; dst = gus_bf; off = i; }
    else if (i < 1572864) { src = wdown; dst = wdown_bf; off = i - 1048576; }
    else { src = wfuse; dst = wfuse_bf; off = i - 1572864; }
    float4 v = *(const float4*)&src[off];
    ushort4 o = {f2bf(v.x), f2bf(v.y), f2bf(v.z), f2bf(v.w)};
    *(ushort4*)&dst[off] = o;
  } else if (bid < 2304) {
    int t8 = (bid - 2048) * 256 + tid;
    uint4 z = {0u, 0u, 0u, 0u};
#pragma unroll
    for (int k = 0; k < 4; ++k) *(uint4*)&resd[(size_t)(t8 + k * 65536) * 8] = z;
  } else {
    // pack A-fragments for sk_mfma: layout [g][p][quad][m16][j] (43 pairs)
    int i2 = (bid - 2304) * 256 + tid;  // 0..704511
    int g = i2 / 22016;
    int r = i2 - g * 22016;
    int p = r >> 9;
    int r5 = r & 511;
    int quad = r5 >> 7, m16 = (r5 >> 3) & 15, j = r & 7;
    int k = quad * 8 + j, tp = k >> 4, ic = k & 15;
    float val = 0.f;
    if (p < 25) {
      int t = 2 * p + tp;
      if (t < 49) val = w7[(size_t)(g * 16 + m16) * 784 + ic * 49 + t];
    } else if (p < 38) {
      int t = 2 * (p - 25) + tp;
      if (t < 25) val = w5[(size_t)(g * 16 + m16) * 400 + ic * 25 + t];
    } else {
      int t = 2 * (p - 38) + tp;
      if (t < 9) val = w3[(size_t)(g * 16 + m16) * 144 + ic * 9 + t];
    }
    Apk_g[i2] = f2bf(val);
  }
}

// ---------------- SKConv via MFMA: grouped conv as 16x1024xK GEMM -----------
// grid 256 = 32 groups x 8 row-slices. A-fragments pre-packed in Apk_g.
__global__ __launch_bounds__(256) void sk_mfma(const float* __restrict__ x,
                                               const ushort* __restrict__ Apk_g,
                                               float* __restrict__ feasRaw) {
  __shared__ ushort xg[10 * 38 * 24];  // [lr][cx][ic pad24] bf16, 18.2 KB
  int bid = blockIdx.x, tid = threadIdx.x;
  int g = bid >> 3, sl = bid & 7, y0 = sl * 4;
  for (int i = tid; i < 4560; i += 256) ((uint*)xg)[i] = 0u;
  __syncthreads();
  for (int i = tid; i < 5120; i += 256) {
    int lr = i >> 9, ic = (i >> 5) & 15, xc = i & 31;
    int y = y0 + lr - 3;
    if ((unsigned)y < 32u)
      xg[(lr * 38 + xc + 3) * 24 + ic] =
          f2bf(x[(size_t)(g * 16 + ic) * 1024 + y * 32 + xc]);
  }
  __syncthreads();
  int wv = tid >> 6, lane = tid & 63, quad = lane >> 4, m16 = lane & 15;
  int qh = (quad & 1) * 8, tp = quad >> 1;
  const ushort* Ag = Apk_g + (size_t)g * 22016;
  f32x4 acc[2][3] = {};
  // k7 (br 2): pairs 0..24
  for (int p = 0; p < 25; ++p) {
    bf16x8 af = *(const bf16x8*)&Ag[(p * 4 + quad) * 128 + m16 * 8];
    int t = 2 * p + tp;
    if (t > 48) t = 48;
    int ky = t / 7, kx = t - ky * 7;
#pragma unroll
    for (int ti = 0; ti < 2; ++ti) {
      int T = wv + ti * 4, tl = T >> 1, x0c = (T & 1) * 16;
      bf16x8 bf = *(const bf16x8*)&xg[((tl + ky) * 38 + x0c + m16 + kx) * 24 + qh];
      acc[ti][2] = __builtin_amdgcn_mfma_f32_16x16x32_bf16(af, bf, acc[ti][2], 0, 0, 0);
    }
  }
  // k5 (br 1): pairs 25..37
  for (int p = 0; p < 13; ++p) {
    bf16x8 af = *(const bf16x8*)&Ag[((p + 25) * 4 + quad) * 128 + m16 * 8];
    int t = 2 * p + tp;
    if (t > 24) t = 24;
    int ky = t / 5, kx = t - ky * 5;
#pragma unroll
    for (int ti = 0; ti < 2; ++ti) {
      int T = wv + ti * 4, tl = T >> 1, x0c = (T & 1) * 16;
      bf16x8 bf =
          *(const bf16x8*)&xg[((tl + ky + 1) * 38 + x0c + m16 + kx + 1) * 24 + qh];
      acc[ti][1] = __builtin_amdgcn_mfma_f32_16x16x32_bf16(af, bf, acc[ti][1], 0, 0, 0);
    }
  }
  // k3 (br 0): pairs 38..42
  for (int p = 0; p < 5; ++p) {
    bf16x8 af = *(const bf16x8*)&Ag[((p + 38) * 4 + quad) * 128 + m16 * 8];
    int t = 2 * p + tp;
    if (t > 8) t = 8;
    int ky = t / 3, kx = t - ky * 3;
#pragma unroll
    for (int ti = 0; ti < 2; ++ti) {
      int T = wv + ti * 4, tl = T >> 1, x0c = (T & 1) * 16;
      bf16x8 bf =
          *(const bf16x8*)&xg[((tl + ky + 2) * 38 + x0c + m16 + kx + 2) * 24 + qh];
      acc[ti][0] = __builtin_amdgcn_mfma_f32_16x16x32_bf16(af, bf, acc[ti][0], 0, 0, 0);
    }
  }
  int cb = g * 16 + quad * 4;
#pragma unroll
  for (int ti = 0; ti < 2; ++ti) {
    int T = wv + ti * 4, tl = T >> 1, x0c = (T & 1) * 16;
    int pos = (y0 + tl) * 32 + x0c + m16;
#pragma unroll
    for (int br = 0; br < 3; ++br)
#pragma unroll
      for (int r = 0; r < 4; ++r)
        feasRaw[(size_t)(br * 512 + cb + r) * 1024 + pos] = acc[ti][br][r];
  }
}

// ---------------- InstanceNorm + ReLU + branch-mean from raw conv -----------
__global__ __launch_bounds__(256) void sk_norm(const float* __restrict__ raw,
                                               float* __restrict__ feas,
                                               float* __restrict__ bmean) {
  __shared__ float red[8];
  int mc = blockIdx.x, tid = threadIdx.x;
  float v[4];
  float s = 0.f, ss = 0.f;
#pragma unroll
  for (int r = 0; r < 4; ++r) {
    v[r] = raw[(size_t)mc * 1024 + tid + r * 256];
    s += v[r];
    ss += v[r] * v[r];
  }
  breduce2(s, ss, red);
  float mean = s * (1.f / 1024.f);
  float var = ss * (1.f / 1024.f) - mean * mean;
  float inv = rsqrtf(var + EPSN);
  float rs = 0.f;
#pragma unroll
  for (int r = 0; r < 4; ++r) {
    float t = (v[r] - mean) * inv;
    t = t > 0.f ? t : 0.f;
    feas[(size_t)mc * 1024 + tid + r * 256] = t;
    rs += t;
  }
  float tot = breduce_sum(rs, red);
  if (tid == 0) bmean[mc] = tot * (1.f / 1024.f);
}

// ---------------- blend + FC-attention; writes res, Zt2 res-half, resd ------
__global__ __launch_bounds__(256) void blend_fc(
    const float* __restrict__ feas, const float* __restrict__ bmean,
    const float* __restrict__ wfc, const float* __restrict__ bfc,
    const float* __restrict__ w0, const float* __restrict__ b0,
    const float* __restrict__ w1, const float* __restrict__ b1,
    const float* __restrict__ w2, const float* __restrict__ b2,
    float* __restrict__ res, ushort* __restrict__ Zt2,
    ushort* __restrict__ resd) {
  __shared__ float sfea[512];
  __shared__ float zpart[8][32];
  __shared__ float zz[32];
  __shared__ float lv[3][32];
  __shared__ float attb[3][32];
  __shared__ float tile[32][33];
  int tid = threadIdx.x;
  int pb = blockIdx.x * 32, cb = blockIdx.y * 32;
  for (int c = tid; c < 512; c += 256)
    sfea[c] = bmean[c] + bmean[512 + c] + bmean[1024 + c];
  __syncthreads();
  {
    int j = tid & 31, seg = tid >> 5;
    float p = 0.f;
    for (int c = seg * 64; c < seg * 64 + 64; ++c) p += sfea[c] * wfc[j * 512 + c];
    zpart[seg][j] = p;
  }
  __syncthreads();
  if (tid < 32) {
    float d = bfc[tid];
#pragma unroll
    for (int s = 0; s < 8; ++s) d += zpart[s][tid];
    zz[tid] = d;
  }
  __syncthreads();
  if (tid < 96) {
    int m = tid >> 5, cl = tid & 31;
    const float* wm = (m == 0) ? w0 : (m == 1) ? w1 : w2;
    const float* bm = (m == 0) ? b0 : (m == 1) ? b1 : b2;
    float l = bm[cb + cl];
#pragma unroll
    for (int j = 0; j < 32; ++j) l += zz[j] * wm[(cb + cl) * 32 + j];
    lv[m][cl] = l;
  }
  __syncthreads();
  if (tid < 32) {
    float l0 = lv[0][tid], l1 = lv[1][tid], l2 = lv[2][tid];
    float mx = fmaxf(l0, fmaxf(l1, l2));
    float e0 = expf(l0 - mx), e1 = expf(l1 - mx), e2 = expf(l2 - mx);
    float inv = 1.f / (e0 + e1 + e2);
    attb[0][tid] = e0 * inv; attb[1][tid] = e1 * inv; attb[2][tid] = e2 * inv;
  }
  __syncthreads();
  int tx = tid & 31, ty = tid >> 5;
  int pos = pb + tx;
  int yy = pos >> 5, xx = pos & 31;
  int ki0 = (yy + 1) & 1, pi0 = (yy + 1 - ki0) >> 1;
  int kj0 = (xx + 1) & 1, pj0 = (xx + 1 - kj0) >> 1;
#pragma unroll
  for (int r = 0; r < 4; ++r) {
    int cl = ty + r * 8;
    int c = cb + cl;
    float v = feas[c * 1024 + pos] * attb[0][cl] +
              feas[(512 + c) * 1024 + pos] * attb[1][cl] +
              feas[(1024 + c) * 1024 + pos] * attb[2][cl];
    res[c * 1024 + pos] = v;
    tile[cl][tx] = v;
    ushort bv16 = f2bf(v);
#pragma unroll
    for (int ai = 0; ai < 2; ++ai) {
      int ki = ki0 + 2 * ai, pi = pi0 - ai;
      if ((unsigned)pi >= 16u) continue;
#pragma unroll
      for (int aj = 0; aj < 2; ++aj) {
        int kj = kj0 + 2 * aj, pj = pj0 - aj;
        if ((unsigned)pj >= 16u) continue;
        resd[((size_t)(ki * 4 + kj) << 17) + (size_t)c * 256 + pi * 16 + pj] = bv16;
      }
    }
  }
  __syncthreads();
#pragma unroll
  for (int r = 0; r < 4; ++r) {
    int pl = ty + r * 8;
    Zt2[(size_t)(pb + pl) * 1024 + 512 + cb + tx] = f2bf(tile[tx][pl]);
  }
}

// ---------------- Gram split-K partials, 16-ch chunks (512 blocks) ----------
__global__ __launch_bounds__(256) void gram_part2(const float* __restrict__ res,
                                                  float* __restrict__ Apart) {
  __shared__ float ch[4][324];
  int tid = threadIdx.x;
  int qb = blockIdx.x * 64, pb = blockIdx.y * 64;
  int kc = blockIdx.z;
  int tx = tid & 15, ty = tid >> 4;
  for (int i = tid; i < 4 * 324; i += 256) ((float*)ch)[i] = 0.f;
  int pi = (pb + ty * 4) >> 4, pj = (pb + ty * 4) & 15;
  int qi = (qb + tx * 4) >> 4, qj = (qb + tx * 4) & 15;
  int lane = tid & 63, wv = tid >> 6;
  int sr = lane >> 2, sc = (lane & 3) * 4;
  float acc[4][4] = {};
  for (int c0 = kc * 16; c0 < kc * 16 + 16; c0 += 4) {
    __syncthreads();
    {
      const float* src = res + (size_t)(c0 + wv) * 1024 + (2 * sr) * 32 + 2 * sc;
      float4 r0a = *(const float4*)src;
      float4 r0b = *(const float4*)(src + 4);
      float4 r1a = *(const float4*)(src + 32);
      float4 r1b = *(const float4*)(src + 36);
      float* dst = &ch[wv][(sr + 1) * 18 + sc + 1];
      dst[0] = 0.25f * (r0a.x + r0a.y + r1a.x + r1a.y);
      dst[1] = 0.25f * (r0a.z + r0a.w + r1a.z + r1a.w);
      dst[2] = 0.25f * (r0b.x + r0b.y + r1b.x + r1b.y);
      dst[3] = 0.25f * (r0b.z + r0b.w + r1b.z + r1b.w);
    }
    __syncthreads();
#pragma unroll
    for (int cc = 0; cc < 4; ++cc) {
      float ps[3][6], qs[3][6];
#pragma unroll
      for (int u = 0; u < 3; ++u) {
        const float* pr = &ch[cc][(pi + u) * 18 + pj];
        const float* qr = &ch[cc][(qi + u) * 18 + qj];
#pragma unroll
        for (int t = 0; t < 6; ++t) { ps[u][t] = pr[t]; qs[u][t] = qr[t]; }
      }
#pragma unroll
      for (int u = 0; u < 3; ++u)
#pragma unroll
        for (int v = 0; v < 3; ++v)
#pragma unroll
          for (int i = 0; i < 4; ++i)
#pragma unroll
            for (int j = 0; j < 4; ++j)
              acc[i][j] += ps[u][v + i] * qs[u][v + j];
    }
  }
#pragma unroll
  for (int i = 0; i < 4; ++i) {
    float4 o4 = {acc[i][0], acc[i][1], acc[i][2], acc[i][3]};
    *(float4*)&Apart[(size_t)kc * 65536 + (pb + ty * 4 + i) * 256 + qb + tx * 4] = o4;
  }
}

// ---------------- softmax + inline diag norm -> attnT bf16 ------------------
__global__ __launch_bounds__(256) void attn_soft3(const float* __restrict__ Apart,
                                                  ushort* __restrict__ attnT) {
  __shared__ float red[8];
  int q = blockIdx.x, t = threadIdx.x;
  float d = 0.f, s = 0.f;
#pragma unroll
  for (int k = 0; k < 32; ++k) {
    d += Apart[(size_t)k * 65536 + t * 257];
    s += Apart[(size_t)k * 65536 + q * 256 + t];
  }
  float invn = 10.f / fmaxf(sqrtf(fmaxf(d, 0.f)), 1e-4f);
  float v = s * invn;
  float mx = breduce_max(v, red);
  float e = expf(v - mx);
  float sm = breduce_sum(e, red);
  attnT[q * 256 + t] = f2bf(e / sm);
}

// ---------------- tconv: 16-batch bf16 MFMA GEMM ----------------------------
__global__ __launch_bounds__(256) void mfma_tconv(const ushort* __restrict__ attnT,
                                                  const ushort* __restrict__ resd,
                                                  float* __restrict__ T) {
  int tid = threadIdx.x;
  int wv = tid >> 6, lane = tid & 63;
  int quad = lane >> 4, m16 = lane & 15;
  int nb = blockIdx.x * 64, qb = blockIdx.y * 64;
  int b = blockIdx.z;
  const ushort* Ap = attnT + (size_t)(qb + wv * 16 + m16) * 256 + quad * 8;
  const ushort* Bp = resd + (size_t)b * 131072 + (size_t)(nb + m16) * 256 + quad * 8;
  f32x4 ac0 = {0.f, 0.f, 0.f, 0.f}, ac1 = ac0, ac2 = ac0, ac3 = ac0;
#pragma unroll 2
  for (int k0 = 0; k0 < 256; k0 += 32) {
    bf16x8 af = *(const bf16x8*)(Ap + k0);
    bf16x8 b0 = *(const bf16x8*)(Bp + k0);
    bf16x8 b1 = *(const bf16x8*)(Bp + 16 * 256 + k0);
    bf16x8 b2 = *(const bf16x8*)(Bp + 32 * 256 + k0);
    bf16x8 b3 = *(const bf16x8*)(Bp + 48 * 256 + k0);
    ac0 = __builtin_amdgcn_mfma_f32_16x16x32_bf16(af, b0, ac0, 0, 0, 0);
    ac1 = __builtin_amdgcn_mfma_f32_16x16x32_bf16(af, b1, ac1, 0, 0, 0);
    ac2 = __builtin_amdgcn_mfma_f32_16x16x32_bf16(af, b2, ac2, 0, 0, 0);
    ac3 = __builtin_amdgcn_mfma_f32_16x16x32_bf16(af, b3, ac3, 0, 0, 0);
  }
  int row = qb + wv * 16 + quad * 4;
  float* Cb = T + (size_t)b * 131072;
  f32x4 accs[4] = {ac0, ac1, ac2, ac3};
#pragma unroll
  for (int nt = 0; nt < 4; ++nt)
#pragma unroll
    for (int r = 0; r < 4; ++r)
      Cb[(size_t)(row + r) * 512 + nb + nt * 16 + m16] = accs[nt][r];
}

// ---------------- combine taps -> orlt, sigt, orlT bf16 (tiled) -------------
__global__ __launch_bounds__(256) void tcomb2(const float* __restrict__ T,
                                              float* __restrict__ orlt,
                                              float* __restrict__ sigt,
                                              ushort* __restrict__ orlT) {
  __shared__ float tl[32][33];
  int nb = blockIdx.x * 32, cb = blockIdx.y * 32;
  int tx = threadIdx.x & 31, ty = threadIdx.x >> 5;
#pragma unroll
  for (int r = 0; r < 4; ++r) {
    int nl = ty + r * 8;
    int n = nb + nl, c = cb + tx;
    int y = n >> 5, x = n & 31;
    int i0 = (y + 1) >> 1, ki0 = (y + 1) & 1;
    int j0 = (x + 1) >> 1, kj0 = (x + 1) & 1;
    float sum = 0.f;
#pragma unroll
    for (int iy = 0; iy < 2; ++iy) {
      int i = i0 - iy, ki = ki0 + 2 * iy;
      if ((unsigned)i >= 16u) continue;
#pragma unroll
      for (int ix = 0; ix < 2; ++ix) {
        int j = j0 - ix, kj = kj0 + 2 * ix;
        if ((unsigned)j >= 16u) continue;
        sum += T[((ki * 4 + kj) * 256 + i * 16 + j) * 512 + c];
      }
    }
    float v = sum * 0.25f;
    orlt[n * 512 + c] = v;
    sigt[n * 512 + c] = 1.f / (1.f + expf(-v));
    tl[nl][tx] = v;
  }
  __syncthreads();
#pragma unroll
  for (int r = 0; r < 4; ++r) {
    int cl = ty + r * 8;
    orlT[(size_t)(cb + cl) * 1024 + nb + tx] = f2bf(tl[tx][cl]);
  }
}

// ---------------- merged: gus GEMM (blocks 0..127) + CSA (128..1151) --------
__global__ __launch_bounds__(256) void gus_csa(
    const ushort* __restrict__ gus_bf, const ushort* __restrict__ orlT,
    const float* __restrict__ sigt, const float* __restrict__ orlt,
    ushort* __restrict__ Zt) {
  __shared__ float red[8];
  __shared__ float a9s[9];
  int tid = threadIdx.x;
  if (blockIdx.x < 128) {
    const int K = 1024;
    int wv = tid >> 6, lane = tid & 63;
    int quad = lane >> 4, m16 = lane & 15;
    int nb = (blockIdx.x & 7) * 64, mb = (blockIdx.x >> 3) * 64;
    const ushort* Ap = gus_bf + (size_t)(mb + wv * 16 + m16) * K + quad * 8;
    const ushort* Bp = orlT + (size_t)(nb + m16) * K + quad * 8;
    f32x4 ac0 = {0.f, 0.f, 0.f, 0.f}, ac1 = ac0, ac2 = ac0, ac3 = ac0;
#pragma unroll 2
    for (int k0 = 0; k0 < K; k0 += 32) {
      bf16x8 af = *(const bf16x8*)(Ap + k0);
      bf16x8 b0 = *(const bf16x8*)(Bp + k0);
      bf16x8 b1 = *(const bf16x8*)(Bp + (size_t)16 * K + k0);
      bf16x8 b2 = *(const bf16x8*)(Bp + (size_t)32 * K + k0);
      bf16x8 b3 = *(const bf16x8*)(Bp + (size_t)48 * K + k0);
      ac0 = __builtin_amdgcn_mfma_f32_16x16x32_bf16(af, b0, ac0, 0, 0, 0);
      ac1 = __builtin_amdgcn_mfma_f32_16x16x32_bf16(af, b1, ac1, 0, 0, 0);
      ac2 = __builtin_amdgcn_mfma_f32_16x16x32_bf16(af, b2, ac2, 0, 0, 0);
      ac3 = __builtin_amdgcn_mfma_f32_16x16x32_bf16(af, b3, ac3, 0, 0, 0);
    }
    int row = mb + wv * 16 + quad * 4;
    f32x4 accs[4] = {ac0, ac1, ac2, ac3};
#pragma unroll
    for (int nt = 0; nt < 4; ++nt) {
      int c = nb + nt * 16 + m16;
#pragma unroll
      for (int r = 0; r < 4; ++r) {
        int p = row + r;
        int pos = ((p & 1) << 9) + c;
        int kk = p >> 1;
        Zt[(size_t)pos * 1024 + kk] = f2bf(accs[nt][r]);
      }
    }
    return;
  }
  int n = blockIdx.x - 128;
  int ny = n >> 5, nx = n & 31;
  int c2 = tid * 2;
  float2 ctr = *(const float2*)&sigt[n * 512 + c2];
  float part[9];
#pragma unroll
  for (int u = 0; u < 3; ++u) {
    int yy = ny + u - 1;
#pragma unroll
    for (int v = 0; v < 3; ++v) {
      int xx = nx + v - 1;
      float2 nb2 = {0.f, 0.f};
      if ((unsigned)yy < 32u && (unsigned)xx < 32u)
        nb2 = *(const float2*)&sigt[(yy * 32 + xx) * 512 + c2];
      part[u * 3 + v] = ctr.x * nb2.x + ctr.y * nb2.y;
    }
  }
  float a[9];
#pragma unroll
  for (int t = 0; t < 9; ++t) a[t] = breduce_sum(part[t], red) * (1.f / 512.f);
  float mx = a[0];
#pragma unroll
  for (int t = 1; t < 9; ++t) mx = fmaxf(mx, a[t]);
  float sum = 0.f;
#pragma unroll
  for (int t = 0; t < 9; ++t) { a[t] = expf(a[t] - mx); sum += a[t]; }
  if (tid == 0) {
    float inv = 1.f / sum;
#pragma unroll
    for (int t = 0; t < 9; ++t) a9s[t] = a[t] * inv;
  }
  __syncthreads();
  float2 acc = {0.f, 0.f};
#pragma unroll
  for (int u = 0; u < 3; ++u) {
    int yy = ny + u - 1;
#pragma unroll
    for (int v = 0; v < 3; ++v) {
      int xx = nx + v - 1;
      if ((unsigned)yy < 32u && (unsigned)xx < 32u) {
        float w = a9s[u * 3 + v];
        float2 ov = *(const float2*)&orlt[(yy * 32 + xx) * 512 + c2];
        acc.x += w * ov.x;
        acc.y += w * ov.y;
      }
    }
  }
  int kk = 512 + (n >> 1);
  int pos0 = ((n & 1) << 9) + c2;
  Zt[(size_t)pos0 * 1024 + kk] = f2bf(acc.x);
  Zt[(size_t)(pos0 + 1) * 1024 + kk] = f2bf(acc.y);
}

// ---------------- K-split bf16 MFMA GEMM: 2 halves -> 2 fp32 partials -------
__global__ __launch_bounds__(256) void mfma_gemm_ks(const ushort* __restrict__ A,
                                                    const ushort* __restrict__ Bt,
                                                    float* __restrict__ Cp,
                                                    int N) {
  const int KF = 1024;
  int tid = threadIdx.x;
  int wv = tid >> 6, lane = tid & 63;
  int quad = lane >> 4, m16 = lane & 15;
  int nb = blockIdx.x * 64, mb = blockIdx.y * 64;
  int kh = blockIdx.z;
  const ushort* Ap = A + (size_t)(mb + wv * 16 + m16) * KF + kh * 512 + quad * 8;
  const ushort* Bp = Bt + (size_t)(nb + m16) * KF + kh * 512 + quad * 8;
  f32x4 ac0 = {0.f, 0.f, 0.f, 0.f}, ac1 = ac0, ac2 = ac0, ac3 = ac0;
#pragma unroll 2
  for (int k0 = 0; k0 < 512; k0 += 32) {
    bf16x8 af = *(const bf16x8*)(Ap + k0);
    bf16x8 b0 = *(const bf16x8*)(Bp + k0);
    bf16x8 b1 = *(const bf16x8*)(Bp + (size_t)16 * KF + k0);
    bf16x8 b2 = *(const bf16x8*)(Bp + (size_t)32 * KF + k0);
    bf16x8 b3 = *(const bf16x8*)(Bp + (size_t)48 * KF + k0);
    ac0 = __builtin_amdgcn_mfma_f32_16x16x32_bf16(af, b0, ac0, 0, 0, 0);
    ac1 = __builtin_amdgcn_mfma_f32_16x16x32_bf16(af, b1, ac1, 0, 0, 0);
    ac2 = __builtin_amdgcn_mfma_f32_16x16x32_bf16(af, b2, ac2, 0, 0, 0);
    ac3 = __builtin_amdgcn_mfma_f32_16x16x32_bf16(af, b3, ac3, 0, 0, 0);
  }
  int row = mb + wv * 16 + quad * 4;
  float* C = Cp + (size_t)kh * 524288;
  f32x4 accs[4] = {ac0, ac1, ac2, ac3};
#pragma unroll
  for (int nt = 0; nt < 4; ++nt)
#pragma unroll
    for (int r = 0; r < 4; ++r)
      C[(size_t)(row + r) * N + nb + nt * 16 + m16] = accs[nt][r];
}

// ---------------- InstanceNorm + LeakyReLU (sum 2 partials) -> Zt2 bf16 -----
__global__ __launch_bounds__(256) void norm_down2(const float* __restrict__ ra,
                                                  ushort* __restrict__ Zt2) {
  __shared__ float red[8];
  int c = blockIdx.x, tid = threadIdx.x;
  float v[4];
  float s = 0.f, ss = 0.f;
#pragma unroll
  for (int r = 0; r < 4; ++r) {
    int i = c * 1024 + tid + r * 256;
    v[r] = ra[i] + ra[524288 + i];
    s += v[r];
    ss += v[r] * v[r];
  }
  breduce2(s, ss, red);
  float mean = s * (1.f / 1024.f);
  float var = ss * (1.f / 1024.f) - mean * mean;
  float inv = rsqrtf(var + EPSN);
#pragma unroll
  for (int r = 0; r < 4; ++r) {
    float t = (v[r] - mean) * inv;
    t = t >= 0.f ? t : 0.2f * t;
    Zt2[(size_t)(tid + r * 256) * 1024 + c] = f2bf(t);
  }
}

// ---------------- final InstanceNorm + LeakyReLU (sum 2 partials) -----------
__global__ __launch_bounds__(256) void norm_leaky2(const float* __restrict__ ra,
                                                   float* __restrict__ out) {
  __shared__ float red[8];
  int c = blockIdx.x, tid = threadIdx.x;
  float v[4];
  float s = 0.f, ss = 0.f;
#pragma unroll
  for (int r = 0; r < 4; ++r) {
    int i = c * 1024 + tid + r * 256;
    v[r] = ra[i] + ra[524288 + i];
    s += v[r];
    ss += v[r] * v[r];
  }
  breduce2(s, ss, red);
  float mean = s * (1.f / 1024.f);
  float var = ss * (1.f / 1024.f) - mean * mean;
  float inv = rsqrtf(var + EPSN);
#pragma unroll
  for (int r = 0; r < 4; ++r) {
    float t = (v[r] - mean) * inv;
    out[c * 1024 + tid + r * 256] = t >= 0.f ? t : 0.2f * t;
  }
}

// ---------------- host launch ------------------------------------------------
extern "C" void kernel_launch(void* const* d_in, const int* in_sizes, int n_in,
                              void* d_out, int out_size, void* d_ws, size_t ws_size,
                              hipStream_t stream) {
  const float* x = (const float*)d_in[0];
  const float* gus = (const float*)d_in[1];
  const float* w3 = (const float*)d_in[2];
  const float* w5 = (const float*)d_in[4];
  const float* w7 = (const float*)d_in[6];
  const float* wfc = (const float*)d_in[8];
  const float* bfc = (const float*)d_in[9];
  const float* w0 = (const float*)d_in[10];
  const float* b0 = (const float*)d_in[11];
  const float* w1 = (const float*)d_in[12];
  const float* b1 = (const float*)d_in[13];
  const float* w2 = (const float*)d_in[14];
  const float* b2 = (const float*)d_in[15];
  const float* wdown = (const float*)d_in[16];
  const float* wfuse = (const float*)d_in[17];

  float* ws = (float*)d_ws;
  float* feas = ws;                      // 1572864 (dead after blend_fc)
  float* rawP = feas + 524288;           // 2x524288 fl partials
  float* bmean = ws + 1572864;           // 1536
  float* res = bmean + 1536;             // 524288
  float* Zt2f = res + 524288;            // 524288 fl
  ushort* Zt2 = (ushort*)Zt2f;
  float* T = Zt2f + 524288;              // 2097152
  float* feasRaw = T;                    // 1572864 fl (dead before gram)
  float* Apart = T;                      // 32x65536 fl (dead before T written)
  ushort* Zt = (ushort*)T;               // (written after tcomb2)
  float* orlt = T + 2097152;             // 524288
  float* sigt = orlt + 524288;           // 524288
  ushort* orlT = (ushort*)(sigt + 524288);        // 262144 fl
  ushort* attnT = (ushort*)(sigt + 786432);       // 32768 fl
  ushort* gus_bf = (ushort*)(sigt + 819200);      // 524288 fl
  ushort* wdown_bf = (ushort*)(sigt + 1343488);   // 262144 fl
  ushort* wfuse_bf = (ushort*)(sigt + 1605632);   // 262144 fl
  ushort* resd = (ushort*)(sigt + 1867776);       // 1048576 fl
  ushort* Apk_g = (ushort*)(sigt + 2916352);      // 704512 ush = 352256 fl

  pre_kernel<<<5056, 256, 0, stream>>>(gus, wdown, wfuse, w3, w5, w7, gus_bf,
                                       wdown_bf, wfuse_bf, resd, Apk_g);
  sk_mfma<<<256, 256, 0, stream>>>(x, Apk_g, feasRaw);
  sk_norm<<<1536, 256, 0, stream>>>(feasRaw, feas, bmean);
  blend_fc<<<dim3(32, 16), 256, 0, stream>>>(feas, bmean, wfc, bfc, w0, b0, w1,
                                             b1, w2, b2, res, Zt2, resd);
  gram_part2<<<dim3(4, 4, 32), 256, 0, stream>>>(res, Apart);
  attn_soft3<<<256, 256, 0, stream>>>(Apart, attnT);
  mfma_tconv<<<dim3(8, 4, 16), 256, 0, stream>>>(attnT, resd, T);
  tcomb2<<<dim3(32, 16), 256, 0, stream>>>(T, orlt, sigt, orlT);
  gus_csa<<<1152, 256, 0, stream>>>(gus_bf, orlT, sigt, orlt, Zt);
  mfma_gemm_ks<<<dim3(16, 8, 2), 256, 0, stream>>>(wdown_bf, Zt, rawP, 1024);
  norm_down2<<<512, 256, 0, stream>>>(rawP, Zt2);
  mfma_gemm_ks<<<dim3(16, 8, 2), 256, 0, stream>>>(wfuse_bf, Zt2, rawP, 1024);
  norm_leaky2<<<512, 256, 0, stream>>>(rawP, (float*)d_out);
}

// Round 16
// 237.765 us; speedup vs baseline: 4.3230x; 1.0045x over previous
//
#include <hip/hip_runtime.h>
#include <math.h>

#define EPSN 1e-5f

typedef __attribute__((ext_vector_type(8))) short bf16x8;
typedef __attribute__((ext_vector_type(4))) float f32x4;

__device__ __forceinline__ ushort f2bf(float f) {
  unsigned u = __float_as_uint(f);
  unsigned r = (u + 0x7fff + ((u >> 16) & 1)) >> 16;
  return (ushort)r;
}
__device__ __forceinline__ float bf2f(ushort h) {
  return __uint_as_float(((unsigned)h) << 16);
}

// ---------------- block-wide reductions (blockDim.x == 256, 4 waves) --------
__device__ __forceinline__ void breduce2(float& a, float& b, float* lds) {
#pragma unroll
  for (int o = 32; o > 0; o >>= 1) {
    a += __shfl_down(a, o);
    b += __shfl_down(b, o);
  }
  int lane = threadIdx.x & 63, wid = threadIdx.x >> 6;
  __syncthreads();
  if (lane == 0) { lds[wid] = a; lds[4 + wid] = b; }
  __syncthreads();
  a = lds[0] + lds[1] + lds[2] + lds[3];
  b = lds[4] + lds[5] + lds[6] + lds[7];
}

__device__ __forceinline__ float breduce_sum(float v, float* lds) {
#pragma unroll
  for (int o = 32; o > 0; o >>= 1) v += __shfl_down(v, o);
  int lane = threadIdx.x & 63, wid = threadIdx.x >> 6;
  __syncthreads();
  if (lane == 0) lds[wid] = v;
  __syncthreads();
  return lds[0] + lds[1] + lds[2] + lds[3];
}

__device__ __forceinline__ float breduce_max(float v, float* lds) {
#pragma unroll
  for (int o = 32; o > 0; o >>= 1) v = fmaxf(v, __shfl_down(v, o));
  int lane = threadIdx.x & 63, wid = threadIdx.x >> 6;
  __syncthreads();
  if (lane == 0) lds[wid] = v;
  __syncthreads();
  return fmaxf(fmaxf(lds[0], lds[1]), fmaxf(lds[2], lds[3]));
}

// ---------------- pre: bf16 converts + resd memset + SK weight packing ------
__global__ void pre_kernel(const float* __restrict__ gus,
                           const float* __restrict__ wdown,
                           const float* __restrict__ wfuse,
                           const float* __restrict__ w3,
                           const float* __restrict__ w5,
                           const float* __restrict__ w7,
                           ushort* __restrict__ gus_bf,
                           ushort* __restrict__ wdown_bf,
                           ushort* __restrict__ wfuse_bf,
                           ushort* __restrict__ resd,
                           ushort* __restrict__ Apk_g) {
  int bid = blockIdx.x, tid = threadIdx.x;
  if (bid < 2048) {
    int i = bid * 1024 + tid * 4;
    const float* src; ushort* dst; int off;
    if (i < 1048576) { src = gus; dst = gus_bf; off = i; }
    else if (i < 1572864) { src = wdown; dst = wdown_bf; off = i - 1048576; }
    else { src = wfuse; dst = wfuse_bf; off = i - 1572864; }
    float4 v = *(const float4*)&src[off];
    ushort4 o = {f2bf(v.x), f2bf(v.y), f2bf(v.z), f2bf(v.w)};
    *(ushort4*)&dst[off] = o;
  } else if (bid < 2304) {
    int t8 = (bid - 2048) * 256 + tid;
    uint4 z = {0u, 0u, 0u, 0u};
#pragma unroll
    for (int k = 0; k < 4; ++k) *(uint4*)&resd[(size_t)(t8 + k * 65536) * 8] = z;
  } else {
    int i2 = (bid - 2304) * 256 + tid;  // 0..704511
    int g = i2 / 22016;
    int r = i2 - g * 22016;
    int p = r >> 9;
    int r5 = r & 511;
    int quad = r5 >> 7, m16 = (r5 >> 3) & 15, j = r & 7;
    int k = quad * 8 + j, tp = k >> 4, ic = k & 15;
    float val = 0.f;
    if (p < 25) {
      int t = 2 * p + tp;
      if (t < 49) val = w7[(size_t)(g * 16 + m16) * 784 + ic * 49 + t];
    } else if (p < 38) {
      int t = 2 * (p - 25) + tp;
      if (t < 25) val = w5[(size_t)(g * 16 + m16) * 400 + ic * 25 + t];
    } else {
      int t = 2 * (p - 38) + tp;
      if (t < 9) val = w3[(size_t)(g * 16 + m16) * 144 + ic * 9 + t];
    }
    Apk_g[i2] = f2bf(val);
  }
}

// ---------------- SKConv via MFMA: grouped conv as 16x1024xK GEMM -----------
// grid 256 = 32 groups x 8 row-slices; output bf16.
__global__ __launch_bounds__(256) void sk_mfma(const float* __restrict__ x,
                                               const ushort* __restrict__ Apk_g,
                                               ushort* __restrict__ feasRawH) {
  __shared__ ushort xg[10 * 38 * 24];  // [lr][cx][ic pad24] bf16, 18.2 KB
  int bid = blockIdx.x, tid = threadIdx.x;
  int g = bid >> 3, sl = bid & 7, y0 = sl * 4;
  for (int i = tid; i < 4560; i += 256) ((uint*)xg)[i] = 0u;
  __syncthreads();
  for (int i = tid; i < 5120; i += 256) {
    int lr = i >> 9, ic = (i >> 5) & 15, xc = i & 31;
    int y = y0 + lr - 3;
    if ((unsigned)y < 32u)
      xg[(lr * 38 + xc + 3) * 24 + ic] =
          f2bf(x[(size_t)(g * 16 + ic) * 1024 + y * 32 + xc]);
  }
  __syncthreads();
  int wv = tid >> 6, lane = tid & 63, quad = lane >> 4, m16 = lane & 15;
  int qh = (quad & 1) * 8, tp = quad >> 1;
  const ushort* Ag = Apk_g + (size_t)g * 22016;
  f32x4 acc[2][3] = {};
  for (int p = 0; p < 25; ++p) {  // k7 (br 2)
    bf16x8 af = *(const bf16x8*)&Ag[(p * 4 + quad) * 128 + m16 * 8];
    int t = 2 * p + tp;
    if (t > 48) t = 48;
    int ky = t / 7, kx = t - ky * 7;
#pragma unroll
    for (int ti = 0; ti < 2; ++ti) {
      int T = wv + ti * 4, tl = T >> 1, x0c = (T & 1) * 16;
      bf16x8 bf = *(const bf16x8*)&xg[((tl + ky) * 38 + x0c + m16 + kx) * 24 + qh];
      acc[ti][2] = __builtin_amdgcn_mfma_f32_16x16x32_bf16(af, bf, acc[ti][2], 0, 0, 0);
    }
  }
  for (int p = 0; p < 13; ++p) {  // k5 (br 1)
    bf16x8 af = *(const bf16x8*)&Ag[((p + 25) * 4 + quad) * 128 + m16 * 8];
    int t = 2 * p + tp;
    if (t > 24) t = 24;
    int ky = t / 5, kx = t - ky * 5;
#pragma unroll
    for (int ti = 0; ti < 2; ++ti) {
      int T = wv + ti * 4, tl = T >> 1, x0c = (T & 1) * 16;
      bf16x8 bf =
          *(const bf16x8*)&xg[((tl + ky + 1) * 38 + x0c + m16 + kx + 1) * 24 + qh];
      acc[ti][1] = __builtin_amdgcn_mfma_f32_16x16x32_bf16(af, bf, acc[ti][1], 0, 0, 0);
    }
  }
  for (int p = 0; p < 5; ++p) {  // k3 (br 0)
    bf16x8 af = *(const bf16x8*)&Ag[((p + 38) * 4 + quad) * 128 + m16 * 8];
    int t = 2 * p + tp;
    if (t > 8) t = 8;
    int ky = t / 3, kx = t - ky * 3;
#pragma unroll
    for (int ti = 0; ti < 2; ++ti) {
      int T = wv + ti * 4, tl = T >> 1, x0c = (T & 1) * 16;
      bf16x8 bf =
          *(const bf16x8*)&xg[((tl + ky + 2) * 38 + x0c + m16 + kx + 2) * 24 + qh];
      acc[ti][0] = __builtin_amdgcn_mfma_f32_16x16x32_bf16(af, bf, acc[ti][0], 0, 0, 0);
    }
  }
  int cb = g * 16 + quad * 4;
#pragma unroll
  for (int ti = 0; ti < 2; ++ti) {
    int T = wv + ti * 4, tl = T >> 1, x0c = (T & 1) * 16;
    int pos = (y0 + tl) * 32 + x0c + m16;
#pragma unroll
    for (int br = 0; br < 3; ++br)
#pragma unroll
      for (int r = 0; r < 4; ++r)
        feasRawH[(size_t)(br * 512 + cb + r) * 1024 + pos] = f2bf(acc[ti][br][r]);
  }
}

// ---------------- InstanceNorm + ReLU + branch-mean (bf16 in/out) -----------
__global__ __launch_bounds__(256) void sk_norm(const ushort* __restrict__ rawH,
                                               ushort* __restrict__ feasH,
                                               float* __restrict__ bmean) {
  __shared__ float red[8];
  int mc = blockIdx.x, tid = threadIdx.x;
  float v[4];
  {
    ushort4 h = *(const ushort4*)&rawH[(size_t)mc * 1024 + tid * 4];
    v[0] = bf2f(h.x); v[1] = bf2f(h.y); v[2] = bf2f(h.z); v[3] = bf2f(h.w);
  }
  float s = 0.f, ss = 0.f;
#pragma unroll
  for (int r = 0; r < 4; ++r) { s += v[r]; ss += v[r] * v[r]; }
  breduce2(s, ss, red);
  float mean = s * (1.f / 1024.f);
  float var = ss * (1.f / 1024.f) - mean * mean;
  float inv = rsqrtf(var + EPSN);
  float rs = 0.f;
  ushort4 o;
#pragma unroll
  for (int r = 0; r < 4; ++r) {
    float t = (v[r] - mean) * inv;
    t = t > 0.f ? t : 0.f;
    ((ushort*)&o)[r] = f2bf(t);
    rs += t;
  }
  *(ushort4*)&feasH[(size_t)mc * 1024 + tid * 4] = o;
  float tot = breduce_sum(rs, red);
  if (tid == 0) bmean[mc] = tot * (1.f / 1024.f);
}

// ---------------- blend + FC-attention; reads bf16 feas ---------------------
__global__ __launch_bounds__(256) void blend_fc(
    const ushort* __restrict__ feasH, const float* __restrict__ bmean,
    const float* __restrict__ wfc, const float* __restrict__ bfc,
    const float* __restrict__ w0, const float* __restrict__ b0,
    const float* __restrict__ w1, const float* __restrict__ b1,
    const float* __restrict__ w2, const float* __restrict__ b2,
    float* __restrict__ res, ushort* __restrict__ Zt2,
    ushort* __restrict__ resd) {
  __shared__ float sfea[512];
  __shared__ float zpart[8][32];
  __shared__ float zz[32];
  __shared__ float lv[3][32];
  __shared__ float attb[3][32];
  __shared__ float tile[32][33];
  int tid = threadIdx.x;
  int pb = blockIdx.x * 32, cb = blockIdx.y * 32;
  for (int c = tid; c < 512; c += 256)
    sfea[c] = bmean[c] + bmean[512 + c] + bmean[1024 + c];
  __syncthreads();
  {
    int j = tid & 31, seg = tid >> 5;
    float p = 0.f;
    for (int c = seg * 64; c < seg * 64 + 64; ++c) p += sfea[c] * wfc[j * 512 + c];
    zpart[seg][j] = p;
  }
  __syncthreads();
  if (tid < 32) {
    float d = bfc[tid];
#pragma unroll
    for (int s = 0; s < 8; ++s) d += zpart[s][tid];
    zz[tid] = d;
  }
  __syncthreads();
  if (tid < 96) {
    int m = tid >> 5, cl = tid & 31;
    const float* wm = (m == 0) ? w0 : (m == 1) ? w1 : w2;
    const float* bm = (m == 0) ? b0 : (m == 1) ? b1 : b2;
    float l = bm[cb + cl];
#pragma unroll
    for (int j = 0; j < 32; ++j) l += zz[j] * wm[(cb + cl) * 32 + j];
    lv[m][cl] = l;
  }
  __syncthreads();
  if (tid < 32) {
    float l0 = lv[0][tid], l1 = lv[1][tid], l2 = lv[2][tid];
    float mx = fmaxf(l0, fmaxf(l1, l2));
    float e0 = expf(l0 - mx), e1 = expf(l1 - mx), e2 = expf(l2 - mx);
    float inv = 1.f / (e0 + e1 + e2);
    attb[0][tid] = e0 * inv; attb[1][tid] = e1 * inv; attb[2][tid] = e2 * inv;
  }
  __syncthreads();
  int tx = tid & 31, ty = tid >> 5;
  int pos = pb + tx;
  int yy = pos >> 5, xx = pos & 31;
  int ki0 = (yy + 1) & 1, pi0 = (yy + 1 - ki0) >> 1;
  int kj0 = (xx + 1) & 1, pj0 = (xx + 1 - kj0) >> 1;
#pragma unroll
  for (int r = 0; r < 4; ++r) {
    int cl = ty + r * 8;
    int c = cb + cl;
    float v = bf2f(feasH[(size_t)c * 1024 + pos]) * attb[0][cl] +
              bf2f(feasH[(size_t)(512 + c) * 1024 + pos]) * attb[1][cl] +
              bf2f(feasH[(size_t)(1024 + c) * 1024 + pos]) * attb[2][cl];
    res[c * 1024 + pos] = v;
    tile[cl][tx] = v;
    ushort bv16 = f2bf(v);
#pragma unroll
    for (int ai = 0; ai < 2; ++ai) {
      int ki = ki0 + 2 * ai, pi = pi0 - ai;
      if ((unsigned)pi >= 16u) continue;
#pragma unroll
      for (int aj = 0; aj < 2; ++aj) {
        int kj = kj0 + 2 * aj, pj = pj0 - aj;
        if ((unsigned)pj >= 16u) continue;
        resd[((size_t)(ki * 4 + kj) << 17) + (size_t)c * 256 + pi * 16 + pj] = bv16;
      }
    }
  }
  __syncthreads();
#pragma unroll
  for (int r = 0; r < 4; ++r) {
    int pl = ty + r * 8;
    Zt2[(size_t)(pb + pl) * 1024 + 512 + cb + tx] = f2bf(tile[tx][pl]);
  }
}

// ---------------- Gram split-K partials, 16-ch chunks (512 blocks) ----------
__global__ __launch_bounds__(256) void gram_part2(const float* __restrict__ res,
                                                  float* __restrict__ Apart) {
  __shared__ float ch[4][324];
  int tid = threadIdx.x;
  int qb = blockIdx.x * 64, pb = blockIdx.y * 64;
  int kc = blockIdx.z;
  int tx = tid & 15, ty = tid >> 4;
  for (int i = tid; i < 4 * 324; i += 256) ((float*)ch)[i] = 0.f;
  int pi = (pb + ty * 4) >> 4, pj = (pb + ty * 4) & 15;
  int qi = (qb + tx * 4) >> 4, qj = (qb + tx * 4) & 15;
  int lane = tid & 63, wv = tid >> 6;
  int sr = lane >> 2, sc = (lane & 3) * 4;
  float acc[4][4] = {};
  for (int c0 = kc * 16; c0 < kc * 16 + 16; c0 += 4) {
    __syncthreads();
    {
      const float* src = res + (size_t)(c0 + wv) * 1024 + (2 * sr) * 32 + 2 * sc;
      float4 r0a = *(const float4*)src;
      float4 r0b = *(const float4*)(src + 4);
      float4 r1a = *(const float4*)(src + 32);
      float4 r1b = *(const float4*)(src + 36);
      float* dst = &ch[wv][(sr + 1) * 18 + sc + 1];
      dst[0] = 0.25f * (r0a.x + r0a.y + r1a.x + r1a.y);
      dst[1] = 0.25f * (r0a.z + r0a.w + r1a.z + r1a.w);
      dst[2] = 0.25f * (r0b.x + r0b.y + r1b.x + r1b.y);
      dst[3] = 0.25f * (r0b.z + r0b.w + r1b.z + r1b.w);
    }
    __syncthreads();
#pragma unroll
    for (int cc = 0; cc < 4; ++cc) {
      float ps[3][6], qs[3][6];
#pragma unroll
      for (int u = 0; u < 3; ++u) {
        const float* pr = &ch[cc][(pi + u) * 18 + pj];
        const float* qr = &ch[cc][(qi + u) * 18 + qj];
#pragma unroll
        for (int t = 0; t < 6; ++t) { ps[u][t] = pr[t]; qs[u][t] = qr[t]; }
      }
#pragma unroll
      for (int u = 0; u < 3; ++u)
#pragma unroll
        for (int v = 0; v < 3; ++v)
#pragma unroll
          for (int i = 0; i < 4; ++i)
#pragma unroll
            for (int j = 0; j < 4; ++j)
              acc[i][j] += ps[u][v + i] * qs[u][v + j];
    }
  }
#pragma unroll
  for (int i = 0; i < 4; ++i) {
    float4 o4 = {acc[i][0], acc[i][1], acc[i][2], acc[i][3]};
    *(float4*)&Apart[(size_t)kc * 65536 + (pb + ty * 4 + i) * 256 + qb + tx * 4] = o4;
  }
}

// ---------------- softmax + inline diag norm -> attnT bf16 ------------------
__global__ __launch_bounds__(256) void attn_soft3(const float* __restrict__ Apart,
                                                  ushort* __restrict__ attnT) {
  __shared__ float red[8];
  int q = blockIdx.x, t = threadIdx.x;
  float d = 0.f, s = 0.f;
#pragma unroll
  for (int k = 0; k < 32; ++k) {
    d += Apart[(size_t)k * 65536 + t * 257];
    s += Apart[(size_t)k * 65536 + q * 256 + t];
  }
  float invn = 10.f / fmaxf(sqrtf(fmaxf(d, 0.f)), 1e-4f);
  float v = s * invn;
  float mx = breduce_max(v, red);
  float e = expf(v - mx);
  float sm = breduce_sum(e, red);
  attnT[q * 256 + t] = f2bf(e / sm);
}

// ---------------- tconv: 16-batch bf16 MFMA GEMM ----------------------------
__global__ __launch_bounds__(256) void mfma_tconv(const ushort* __restrict__ attnT,
                                                  const ushort* __restrict__ resd,
                                                  float* __restrict__ T) {
  int tid = threadIdx.x;
  int wv = tid >> 6, lane = tid & 63;
  int quad = lane >> 4, m16 = lane & 15;
  int nb = blockIdx.x * 64, qb = blockIdx.y * 64;
  int b = blockIdx.z;
  const ushort* Ap = attnT + (size_t)(qb + wv * 16 + m16) * 256 + quad * 8;
  const ushort* Bp = resd + (size_t)b * 131072 + (size_t)(nb + m16) * 256 + quad * 8;
  f32x4 ac0 = {0.f, 0.f, 0.f, 0.f}, ac1 = ac0, ac2 = ac0, ac3 = ac0;
#pragma unroll 2
  for (int k0 = 0; k0 < 256; k0 += 32) {
    bf16x8 af = *(const bf16x8*)(Ap + k0);
    bf16x8 b0 = *(const bf16x8*)(Bp + k0);
    bf16x8 b1 = *(const bf16x8*)(Bp + 16 * 256 + k0);
    bf16x8 b2 = *(const bf16x8*)(Bp + 32 * 256 + k0);
    bf16x8 b3 = *(const bf16x8*)(Bp + 48 * 256 + k0);
    ac0 = __builtin_amdgcn_mfma_f32_16x16x32_bf16(af, b0, ac0, 0, 0, 0);
    ac1 = __builtin_amdgcn_mfma_f32_16x16x32_bf16(af, b1, ac1, 0, 0, 0);
    ac2 = __builtin_amdgcn_mfma_f32_16x16x32_bf16(af, b2, ac2, 0, 0, 0);
    ac3 = __builtin_amdgcn_mfma_f32_16x16x32_bf16(af, b3, ac3, 0, 0, 0);
  }
  int row = qb + wv * 16 + quad * 4;
  float* Cb = T + (size_t)b * 131072;
  f32x4 accs[4] = {ac0, ac1, ac2, ac3};
#pragma unroll
  for (int nt = 0; nt < 4; ++nt)
#pragma unroll
    for (int r = 0; r < 4; ++r)
      Cb[(size_t)(row + r) * 512 + nb + nt * 16 + m16] = accs[nt][r];
}

// ---------------- combine taps -> orlt, sigt, orlT bf16 (tiled) -------------
__global__ __launch_bounds__(256) void tcomb2(const float* __restrict__ T,
                                              float* __restrict__ orlt,
                                              float* __restrict__ sigt,
                                              ushort* __restrict__ orlT) {
  __shared__ float tl[32][33];
  int nb = blockIdx.x * 32, cb = blockIdx.y * 32;
  int tx = threadIdx.x & 31, ty = threadIdx.x >> 5;
#pragma unroll
  for (int r = 0; r < 4; ++r) {
    int nl = ty + r * 8;
    int n = nb + nl, c = cb + tx;
    int y = n >> 5, x = n & 31;
    int i0 = (y + 1) >> 1, ki0 = (y + 1) & 1;
    int j0 = (x + 1) >> 1, kj0 = (x + 1) & 1;
    float sum = 0.f;
#pragma unroll
    for (int iy = 0; iy < 2; ++iy) {
      int i = i0 - iy, ki = ki0 + 2 * iy;
      if ((unsigned)i >= 16u) continue;
#pragma unroll
      for (int ix = 0; ix < 2; ++ix) {
        int j = j0 - ix, kj = kj0 + 2 * ix;
        if ((unsigned)j >= 16u) continue;
        sum += T[((ki * 4 + kj) * 256 + i * 16 + j) * 512 + c];
      }
    }
    float v = sum * 0.25f;
    orlt[n * 512 + c] = v;
    sigt[n * 512 + c] = 1.f / (1.f + expf(-v));
    tl[nl][tx] = v;
  }
  __syncthreads();
#pragma unroll
  for (int r = 0; r < 4; ++r) {
    int cl = ty + r * 8;
    orlT[(size_t)(cb + cl) * 1024 + nb + tx] = f2bf(tl[tx][cl]);
  }
}

// ---------------- merged: gus GEMM (blocks 0..127) + CSA (128..1151) --------
__global__ __launch_bounds__(256) void gus_csa(
    const ushort* __restrict__ gus_bf, const ushort* __restrict__ orlT,
    const float* __restrict__ sigt, const float* __restrict__ orlt,
    ushort* __restrict__ Zt) {
  __shared__ float red9[4][9];
  __shared__ float a9s[9];
  int tid = threadIdx.x;
  if (blockIdx.x < 128) {
    const int K = 1024;
    int wv = tid >> 6, lane = tid & 63;
    int quad = lane >> 4, m16 = lane & 15;
    int nb = (blockIdx.x & 7) * 64, mb = (blockIdx.x >> 3) * 64;
    const ushort* Ap = gus_bf + (size_t)(mb + wv * 16 + m16) * K + quad * 8;
    const ushort* Bp = orlT + (size_t)(nb + m16) * K + quad * 8;
    f32x4 ac0 = {0.f, 0.f, 0.f, 0.f}, ac1 = ac0, ac2 = ac0, ac3 = ac0;
#pragma unroll 2
    for (int k0 = 0; k0 < K; k0 += 32) {
      bf16x8 af = *(const bf16x8*)(Ap + k0);
      bf16x8 b0 = *(const bf16x8*)(Bp + k0);
      bf16x8 b1 = *(const bf16x8*)(Bp + (size_t)16 * K + k0);
      bf16x8 b2 = *(const bf16x8*)(Bp + (size_t)32 * K + k0);
      bf16x8 b3 = *(const bf16x8*)(Bp + (size_t)48 * K + k0);
      ac0 = __builtin_amdgcn_mfma_f32_16x16x32_bf16(af, b0, ac0, 0, 0, 0);
      ac1 = __builtin_amdgcn_mfma_f32_16x16x32_bf16(af, b1, ac1, 0, 0, 0);
      ac2 = __builtin_amdgcn_mfma_f32_16x16x32_bf16(af, b2, ac2, 0, 0, 0);
      ac3 = __builtin_amdgcn_mfma_f32_16x16x32_bf16(af, b3, ac3, 0, 0, 0);
    }
    int row = mb + wv * 16 + quad * 4;
    f32x4 accs[4] = {ac0, ac1, ac2, ac3};
#pragma unroll
    for (int nt = 0; nt < 4; ++nt) {
      int c = nb + nt * 16 + m16;
#pragma unroll
      for (int r = 0; r < 4; ++r) {
        int p = row + r;
        int pos = ((p & 1) << 9) + c;
        int kk = p >> 1;
        Zt[(size_t)pos * 1024 + kk] = f2bf(accs[nt][r]);
      }
    }
    return;
  }
  int n = blockIdx.x - 128;
  int ny = n >> 5, nx = n & 31;
  int c2 = tid * 2;
  int lane = tid & 63, wid = tid >> 6;
  float2 ctr = *(const float2*)&sigt[n * 512 + c2];
  float part[9];
#pragma unroll
  for (int u = 0; u < 3; ++u) {
    int yy = ny + u - 1;
#pragma unroll
    for (int v = 0; v < 3; ++v) {
      int xx = nx + v - 1;
      float2 nb2 = {0.f, 0.f};
      if ((unsigned)yy < 32u && (unsigned)xx < 32u)
        nb2 = *(const float2*)&sigt[(yy * 32 + xx) * 512 + c2];
      part[u * 3 + v] = ctr.x * nb2.x + ctr.y * nb2.y;
    }
  }
  // batched 9-way reduction: one LDS round instead of nine
#pragma unroll
  for (int t = 0; t < 9; ++t)
#pragma unroll
    for (int o = 32; o > 0; o >>= 1) part[t] += __shfl_down(part[t], o);
  if (lane == 0)
#pragma unroll
    for (int t = 0; t < 9; ++t) red9[wid][t] = part[t];
  __syncthreads();
  if (tid == 0) {
    float a[9];
#pragma unroll
    for (int t = 0; t < 9; ++t)
      a[t] = (red9[0][t] + red9[1][t] + red9[2][t] + red9[3][t]) * (1.f / 512.f);
    float mx = a[0];
#pragma unroll
    for (int t = 1; t < 9; ++t) mx = fmaxf(mx, a[t]);
    float sum = 0.f;
#pragma unroll
    for (int t = 0; t < 9; ++t) { a[t] = expf(a[t] - mx); sum += a[t]; }
    float inv = 1.f / sum;
#pragma unroll
    for (int t = 0; t < 9; ++t) a9s[t] = a[t] * inv;
  }
  __syncthreads();
  float2 acc = {0.f, 0.f};
#pragma unroll
  for (int u = 0; u < 3; ++u) {
    int yy = ny + u - 1;
#pragma unroll
    for (int v = 0; v < 3; ++v) {
      int xx = nx + v - 1;
      if ((unsigned)yy < 32u && (unsigned)xx < 32u) {
        float w = a9s[u * 3 + v];
        float2 ov = *(const float2*)&orlt[(yy * 32 + xx) * 512 + c2];
        acc.x += w * ov.x;
        acc.y += w * ov.y;
      }
    }
  }
  int kk = 512 + (n >> 1);
  int pos0 = ((n & 1) << 9) + c2;
  Zt[(size_t)pos0 * 1024 + kk] = f2bf(acc.x);
  Zt[(size_t)(pos0 + 1) * 1024 + kk] = f2bf(acc.y);
}

// ---------------- K-split bf16 MFMA GEMM: 2 halves -> 2 fp32 partials -------
__global__ __launch_bounds__(256) void mfma_gemm_ks(const ushort* __restrict__ A,
                                                    const ushort* __restrict__ Bt,
                                                    float* __restrict__ Cp,
                                                    int N) {
  const int KF = 1024;
  int tid = threadIdx.x;
  int wv = tid >> 6, lane = tid & 63;
  int quad = lane >> 4, m16 = lane & 15;
  int nb = blockIdx.x * 64, mb = blockIdx.y * 64;
  int kh = blockIdx.z;
  const ushort* Ap = A + (size_t)(mb + wv * 16 + m16) * KF + kh * 512 + quad * 8;
  const ushort* Bp = Bt + (size_t)(nb + m16) * KF + kh * 512 + quad * 8;
  f32x4 ac0 = {0.f, 0.f, 0.f, 0.f}, ac1 = ac0, ac2 = ac0, ac3 = ac0;
#pragma unroll 2
  for (int k0 = 0; k0 < 512; k0 += 32) {
    bf16x8 af = *(const bf16x8*)(Ap + k0);
    bf16x8 b0 = *(const bf16x8*)(Bp + k0);
    bf16x8 b1 = *(const bf16x8*)(Bp + (size_t)16 * KF + k0);
    bf16x8 b2 = *(const bf16x8*)(Bp + (size_t)32 * KF + k0);
    bf16x8 b3 = *(const bf16x8*)(Bp + (size_t)48 * KF + k0);
    ac0 = __builtin_amdgcn_mfma_f32_16x16x32_bf16(af, b0, ac0, 0, 0, 0);
    ac1 = __builtin_amdgcn_mfma_f32_16x16x32_bf16(af, b1, ac1, 0, 0, 0);
    ac2 = __builtin_amdgcn_mfma_f32_16x16x32_bf16(af, b2, ac2, 0, 0, 0);
    ac3 = __builtin_amdgcn_mfma_f32_16x16x32_bf16(af, b3, ac3, 0, 0, 0);
  }
  int row = mb + wv * 16 + quad * 4;
  float* C = Cp + (size_t)kh * 524288;
  f32x4 accs[4] = {ac0, ac1, ac2, ac3};
#pragma unroll
  for (int nt = 0; nt < 4; ++nt)
#pragma unroll
    for (int r = 0; r < 4; ++r)
      C[(size_t)(row + r) * N + nb + nt * 16 + m16] = accs[nt][r];
}

// ---------------- InstanceNorm + LeakyReLU (sum 2 partials) -> Zt2 bf16 -----
__global__ __launch_bounds__(256) void norm_down2(const float* __restrict__ ra,
                                                  ushort* __restrict__ Zt2) {
  __shared__ float red[8];
  int c = blockIdx.x, tid = threadIdx.x;
  float v[4];
  float s = 0.f, ss = 0.f;
#pragma unroll
  for (int r = 0; r < 4; ++r) {
    int i = c * 1024 + tid + r * 256;
    v[r] = ra[i] + ra[524288 + i];
    s += v[r];
    ss += v[r] * v[r];
  }
  breduce2(s, ss, red);
  float mean = s * (1.f / 1024.f);
  float var = ss * (1.f / 1024.f) - mean * mean;
  float inv = rsqrtf(var + EPSN);
#pragma unroll
  for (int r = 0; r < 4; ++r) {
    float t = (v[r] - mean) * inv;
    t = t >= 0.f ? t : 0.2f * t;
    Zt2[(size_t)(tid + r * 256) * 1024 + c] = f2bf(t);
  }
}

// ---------------- final InstanceNorm + LeakyReLU (sum 2 partials) -----------
__global__ __launch_bounds__(256) void norm_leaky2(const float* __restrict__ ra,
                                                   float* __restrict__ out) {
  __shared__ float red[8];
  int c = blockIdx.x, tid = threadIdx.x;
  float v[4];
  float s = 0.f, ss = 0.f;
#pragma unroll
  for (int r = 0; r < 4; ++r) {
    int i = c * 1024 + tid + r * 256;
    v[r] = ra[i] + ra[524288 + i];
    s += v[r];
    ss += v[r] * v[r];
  }
  breduce2(s, ss, red);
  float mean = s * (1.f / 1024.f);
  float var = ss * (1.f / 1024.f) - mean * mean;
  float inv = rsqrtf(var + EPSN);
#pragma unroll
  for (int r = 0; r < 4; ++r) {
    float t = (v[r] - mean) * inv;
    out[c * 1024 + tid + r * 256] = t >= 0.f ? t : 0.2f * t;
  }
}

// ---------------- host launch ------------------------------------------------
extern "C" void kernel_launch(void* const* d_in, const int* in_sizes, int n_in,
                              void* d_out, int out_size, void* d_ws, size_t ws_size,
                              hipStream_t stream) {
  const float* x = (const float*)d_in[0];
  const float* gus = (const float*)d_in[1];
  const float* w3 = (const float*)d_in[2];
  const float* w5 = (const float*)d_in[4];
  const float* w7 = (const float*)d_in[6];
  const float* wfc = (const float*)d_in[8];
  const float* bfc = (const float*)d_in[9];
  const float* w0 = (const float*)d_in[10];
  const float* b0 = (const float*)d_in[11];
  const float* w1 = (const float*)d_in[12];
  const float* b1 = (const float*)d_in[13];
  const float* w2 = (const float*)d_in[14];
  const float* b2 = (const float*)d_in[15];
  const float* wdown = (const float*)d_in[16];
  const float* wfuse = (const float*)d_in[17];

  float* ws = (float*)d_ws;
  ushort* feasH = (ushort*)ws;           // 1572864 ush = 786432 fl (dead after blend_fc)
  float* rawP = ws + 786432;             // 2x524288 fl partials (written late)
  float* bmean = ws + 1835008;           // 1536
  float* res = bmean + 1536;             // 524288
  float* Zt2f = res + 524288;            // 524288 fl
  ushort* Zt2 = (ushort*)Zt2f;
  float* T = Zt2f + 524288;              // 2097152
  ushort* feasRawH = (ushort*)T;         // 1572864 ush (dead before gram)
  float* Apart = T;                      // 32x65536 fl (dead before T written)
  ushort* Zt = (ushort*)T;               // (written after tcomb2)
  float* orlt = T + 2097152;             // 524288
  float* sigt = orlt + 524288;           // 524288
  ushort* orlT = (ushort*)(sigt + 524288);        // 262144 fl
  ushort* attnT = (ushort*)(sigt + 786432);       // 32768 fl
  ushort* gus_bf = (ushort*)(sigt + 819200);      // 524288 fl
  ushort* wdown_bf = (ushort*)(sigt + 1343488);   // 262144 fl
  ushort* wfuse_bf = (ushort*)(sigt + 1605632);   // 262144 fl
  ushort* resd = (ushort*)(sigt + 1867776);       // 1048576 fl
  ushort* Apk_g = (ushort*)(sigt + 2916352);      // 704512 ush

  pre_kernel<<<5056, 256, 0, stream>>>(gus, wdown, wfuse, w3, w5, w7, gus_bf,
                                       wdown_bf, wfuse_bf, resd, Apk_g);
  sk_mfma<<<256, 256, 0, stream>>>(x, Apk_g, feasRawH);
  sk_norm<<<1536, 256, 0, stream>>>(feasRawH, feasH, bmean);
  blend_fc<<<dim3(32, 16), 256, 0, stream>>>(feasH, bmean, wfc, bfc, w0, b0, w1,
                                             b1, w2, b2, res, Zt2, resd);
  gram_part2<<<dim3(4, 4, 32), 256, 0, stream>>>(res, Apart);
  attn_soft3<<<256, 256, 0, stream>>>(Apart, attnT);
  mfma_tconv<<<dim3(8, 4, 16), 256, 0, stream>>>(attnT, resd, T);
  tcomb2<<<dim3(32, 16), 256, 0, stream>>>(T, orlt, sigt, orlT);
  gus_csa<<<1152, 256, 0, stream>>>(gus_bf, orlT, sigt, orlt, Zt);
  mfma_gemm_ks<<<dim3(16, 8, 2), 256, 0, stream>>>(wdown_bf, Zt, rawP, 1024);
  norm_down2<<<512, 256, 0, stream>>>(rawP, Zt2);
  mfma_gemm_ks<<<dim3(16, 8, 2), 256, 0, stream>>>(wfuse_bf, Zt2, rawP, 1024);
  norm_leaky2<<<512, 256, 0, stream>>>(rawP, (float*)d_out);
}